// Round 1
// baseline (3766.542 us; speedup 1.0000x reference)
//
#include <hip/hip_runtime.h>
#include <stdint.h>

#define N_ROWS 65536
#define DIM 1024
#define HID 128
#define FD 512
#define KCB 1024
#define HALFCNT 33554432u

#define OFF_Q    1
#define OFF_PERP 33554433
#define OFF_ENC  33554434
#define OFF_ND   100663298

__device__ __forceinline__ uint32_t rotl32(uint32_t v, int r) { return (v << r) | (v >> (32 - r)); }

// JAX threefry2x32 with key (0, 42)
__device__ __forceinline__ void threefry(uint32_t c0, uint32_t c1, uint32_t& o0, uint32_t& o1) {
    const uint32_t ks0 = 0u, ks1 = 42u, ks2 = 0x1BD11BDAu ^ 0u ^ 42u;
    uint32_t x0 = c0 + ks0, x1 = c1 + ks1;
#define TFR(r) x0 += x1; x1 = rotl32(x1, r); x1 ^= x0;
    TFR(13) TFR(15) TFR(26) TFR(6)  x0 += ks1; x1 += ks2 + 1u;
    TFR(17) TFR(29) TFR(16) TFR(24) x0 += ks2; x1 += ks0 + 2u;
    TFR(13) TFR(15) TFR(26) TFR(6)  x0 += ks0; x1 += ks1 + 3u;
    TFR(17) TFR(29) TFR(16) TFR(24) x0 += ks1; x1 += ks2 + 4u;
    TFR(13) TFR(15) TFR(26) TFR(6)  x0 += ks2; x1 += ks0 + 5u;
#undef TFR
    o0 = x0; o1 = x1;
}

// JAX uniform->gumbel semantics: u = max(FLT_MIN, bitcast(0x3F800000|(b>>9)) - 1.0f); g = -log(-log(u))
__device__ __forceinline__ double gumbel_bits(uint32_t b) {
    uint32_t m = b >> 9;
    double u = m ? (double)m * 1.1920928955078125e-07 /*2^-23, exact*/ : 1.1754943508222875e-38;
    return -log(-log(u));
}

__global__ void k_init(int* __restrict__ counts, double* __restrict__ loss_acc) {
    int t = threadIdx.x;
    for (int k = t; k < KCB; k += 256) counts[k] = 0;
    if (t == 0) *loss_acc = 0.0;
}

// h64 = relu(X @ W1 + b1), f64. Tile: 16 rows x 128 cols per block (256 thr).
__global__ __launch_bounds__(256) void k_gemm1(const float* __restrict__ X, const float* __restrict__ W1,
                                               const float* __restrict__ b1, double* __restrict__ h64) {
    __shared__ float xs[16][256];
    int t = threadIdx.x;
    int c = t & 127, rg = t >> 7;
    int nb = blockIdx.x * 16;
    double acc[8] = {0, 0, 0, 0, 0, 0, 0, 0};
    for (int j0 = 0; j0 < DIM; j0 += 256) {
        for (int e = t; e < 1024; e += 256) {
            int r = e >> 6, j4 = e & 63;
            *(float4*)&xs[r][j4 * 4] = *(const float4*)&X[(size_t)(nb + r) * DIM + j0 + j4 * 4];
        }
        __syncthreads();
        for (int j = 0; j < 256; j += 2) {
            double w0 = (double)W1[(size_t)(j0 + j) * HID + c];
            double w1 = (double)W1[(size_t)(j0 + j + 1) * HID + c];
            #pragma unroll
            for (int r = 0; r < 8; ++r) {
                float2 xv = *(const float2*)&xs[rg * 8 + r][j];
                acc[r] = fma((double)xv.x, w0, acc[r]);
                acc[r] = fma((double)xv.y, w1, acc[r]);
            }
        }
        __syncthreads();
    }
    double bv = (double)b1[c];
    #pragma unroll
    for (int r = 0; r < 8; ++r) {
        double v = acc[r] + bv;
        v = v > 0.0 ? v : 0.0;
        h64[(size_t)(nb + rg * 8 + r) * HID + c] = v;
    }
}

// z = h64 @ W2 + b2 -> f32 z (output region), plus exact f64 row norms zz from UNROUNDED z.
// Tile: 8 rows x 512 cols per block.
__global__ __launch_bounds__(256) void k_gemm2(const double* __restrict__ h64, const float* __restrict__ W2,
                                               const float* __restrict__ b2, float* __restrict__ z,
                                               double* __restrict__ zz) {
    int t = threadIdx.x;
    int n0 = blockIdx.x * 8;
    double acc[8][2] = {};
    for (int j = 0; j < HID; ++j) {
        double w0 = (double)W2[(size_t)j * FD + t];
        double w1 = (double)W2[(size_t)j * FD + t + 256];
        #pragma unroll
        for (int r = 0; r < 8; ++r) {
            double hv = h64[(size_t)(n0 + r) * HID + j];
            acc[r][0] = fma(hv, w0, acc[r][0]);
            acc[r][1] = fma(hv, w1, acc[r][1]);
        }
    }
    double b0 = (double)b2[t], b1v = (double)b2[t + 256];
    double p[8];
    #pragma unroll
    for (int r = 0; r < 8; ++r) {
        double z0 = acc[r][0] + b0, z1 = acc[r][1] + b1v;
        z[(size_t)(n0 + r) * FD + t] = (float)z0;
        z[(size_t)(n0 + r) * FD + t + 256] = (float)z1;
        p[r] = z0 * z0 + z1 * z1;
    }
    int lane = t & 63, w = t >> 6;
    __shared__ double red[8][4];
    #pragma unroll
    for (int r = 0; r < 8; ++r) {
        double v = p[r];
        for (int off = 32; off; off >>= 1) v += __shfl_down(v, off, 64);
        if (lane == 0) red[r][w] = v;
    }
    __syncthreads();
    if (t < 8) zz[n0 + t] = red[t][0] + red[t][1] + red[t][2] + red[t][3];
}

__global__ void k_ccnorm(const float* __restrict__ cb, double* __restrict__ cc) {
    int k = blockIdx.x, lane = threadIdx.x;
    double s = 0.0;
    for (int f = lane; f < FD; f += 64) {
        double v = (double)cb[(size_t)k * FD + f];
        s = fma(v, v, s);
    }
    for (int off = 32; off; off >>= 1) s += __shfl_down(s, off, 64);
    if (lane == 0) cc[k] = s;
}

// neg-distances = -((zz + cc) - 2*dot) in f64, stored as f32 hi (output) + f32 lo (scratch region).
// Tile: 32 n x 64 k, f64 accumulate, LDS-staged.
__global__ __launch_bounds__(256) void k_gemm3(const float* __restrict__ z, const float* __restrict__ cb,
                                               const double* __restrict__ zz, const double* __restrict__ cc,
                                               float* __restrict__ ndhi, float* __restrict__ ndlo) {
    __shared__ float zs[32][66];
    __shared__ float cs[64][66];
    int t = threadIdx.x;
    int bk = blockIdx.x & 15;
    int bn = blockIdx.x >> 4;
    int n0 = bn * 32, k0 = bk * 64;
    int tc = t & 31, tr = t >> 5;
    double acc[4][2] = {};
    for (int f0 = 0; f0 < FD; f0 += 64) {
        for (int e = t; e < 32 * 64; e += 256) {
            int r = e >> 6, j = e & 63;
            zs[r][j] = z[(size_t)(n0 + r) * FD + f0 + j];
        }
        for (int e = t; e < 64 * 64; e += 256) {
            int kk = e >> 6, j = e & 63;
            cs[kk][j] = cb[(size_t)(k0 + kk) * FD + f0 + j];
        }
        __syncthreads();
        for (int j = 0; j < 64; j += 2) {
            float2 cA = *(const float2*)&cs[tc][j];
            float2 cB = *(const float2*)&cs[tc + 32][j];
            double c00 = (double)cA.x, c01 = (double)cA.y;
            double c10 = (double)cB.x, c11 = (double)cB.y;
            #pragma unroll
            for (int i = 0; i < 4; ++i) {
                float2 zv = *(const float2*)&zs[tr * 4 + i][j];
                double zx = (double)zv.x, zy = (double)zv.y;
                acc[i][0] = fma(zx, c00, acc[i][0]);
                acc[i][0] = fma(zy, c01, acc[i][0]);
                acc[i][1] = fma(zx, c10, acc[i][1]);
                acc[i][1] = fma(zy, c11, acc[i][1]);
            }
        }
        __syncthreads();
    }
    #pragma unroll
    for (int i = 0; i < 4; ++i) {
        int n = n0 + tr * 4 + i;
        double zn = zz[n];
        #pragma unroll
        for (int q = 0; q < 2; ++q) {
            int k = k0 + tc + q * 32;
            double d = (zn + cc[k]) - 2.0 * acc[i][q];
            double nv = -d;
            float hi = (float)nv;
            ndhi[(size_t)n * KCB + k] = hi;
            ndlo[(size_t)n * KCB + k] = (float)(nv - (double)hi);
        }
    }
}

// Per block: rows n and n+32768 share threefry counters (JAX even-split). Argmax of logits+gumbel.
__global__ __launch_bounds__(256) void k_sample(const float* __restrict__ ndhi, const float* __restrict__ ndlo,
                                                int* __restrict__ idx, int* __restrict__ counts) {
    int n = blockIdx.x;
    int t = threadIdx.x;
    double best0 = -1e300, best1 = -1e300;
    int bi0 = 0, bi1 = 0;
    for (int k = t; k < KCB; k += 256) {
        uint32_t ctr = (uint32_t)(n * KCB + k);
        uint32_t r0, r1;
        threefry(ctr, ctr + HALFCNT, r0, r1);
        double g0 = gumbel_bits(r0), g1 = gumbel_bits(r1);
        size_t i0 = (size_t)n * KCB + k;
        size_t i1 = (size_t)(n + 32768) * KCB + k;
        double s0 = ((double)ndhi[i0] + (double)ndlo[i0]) / 0.1 + g0;
        double s1 = ((double)ndhi[i1] + (double)ndlo[i1]) / 0.1 + g1;
        if (s0 > best0) { best0 = s0; bi0 = k; }
        if (s1 > best1) { best1 = s1; bi1 = k; }
    }
    __shared__ double sv0[256], sv1[256];
    __shared__ int si0[256], si1[256];
    sv0[t] = best0; si0[t] = bi0; sv1[t] = best1; si1[t] = bi1;
    __syncthreads();
    for (int off = 128; off; off >>= 1) {
        if (t < off) {
            if (sv0[t + off] > sv0[t] || (sv0[t + off] == sv0[t] && si0[t + off] < si0[t])) {
                sv0[t] = sv0[t + off]; si0[t] = si0[t + off];
            }
            if (sv1[t + off] > sv1[t] || (sv1[t + off] == sv1[t] && si1[t + off] < si1[t])) {
                sv1[t] = sv1[t + off]; si1[t] = si1[t + off];
            }
        }
        __syncthreads();
    }
    if (t == 0) {
        idx[n] = si0[0];
        idx[n + 32768] = si1[0];
        atomicAdd(&counts[si0[0]], 1);
        atomicAdd(&counts[si1[0]], 1);
    }
}

// In-place: q_st = z + (c[idx]-z) (f32, JAX order), and f64 loss accumulation of (c-z)^2.
__global__ __launch_bounds__(256) void k_quant(float* __restrict__ qz, const float* __restrict__ cb,
                                               const int* __restrict__ idx, double* __restrict__ loss_acc) {
    size_t tid = (size_t)blockIdx.x * 256 + threadIdx.x;
    size_t stride = (size_t)gridDim.x * 256;
    double local = 0.0;
    for (size_t ii = tid; ii < (size_t)N_ROWS * FD; ii += stride) {
        int n = (int)(ii >> 9);
        int f = (int)(ii & 511);
        float zv = qz[ii];
        float cv = cb[(size_t)idx[n] * FD + f];
        float d1 = cv - zv;
        qz[ii] = zv + d1;
        double dd = (double)cv - (double)zv;
        local = fma(dd, dd, local);
    }
    for (int off = 32; off; off >>= 1) local += __shfl_down(local, off, 64);
    __shared__ double red[4];
    int lane = threadIdx.x & 63, w = threadIdx.x >> 6;
    if (lane == 0) red[w] = local;
    __syncthreads();
    if (threadIdx.x == 0) atomicAdd(loss_acc, red[0] + red[1] + red[2] + red[3]);
}

__global__ void k_zero_enc(float* __restrict__ enc) {
    size_t i = (size_t)blockIdx.x * blockDim.x + threadIdx.x;
    size_t stride = (size_t)gridDim.x * blockDim.x;
    float2* p = (float2*)enc;  // enc region is 8B-aligned
    size_t n2 = (size_t)N_ROWS * KCB / 2;
    float2 zv = make_float2(0.f, 0.f);
    for (size_t j = i; j < n2; j += stride) p[j] = zv;
}

__global__ void k_scatter(float* __restrict__ enc, const int* __restrict__ idx) {
    int n = blockIdx.x * 256 + threadIdx.x;
    enc[(size_t)n * KCB + idx[n]] = 1.0f;
}

__global__ void k_scalars(const int* __restrict__ counts, const double* __restrict__ loss_acc,
                          float* __restrict__ out) {
    int t = threadIdx.x;
    double s = 0.0;
    for (int k = t; k < KCB; k += 256) {
        double p = (double)counts[k] * (1.0 / 65536.0);
        s += p * log(p + 1e-10);
    }
    for (int off = 32; off; off >>= 1) s += __shfl_down(s, off, 64);
    __shared__ double red[4];
    int lane = t & 63, w = t >> 6;
    if (lane == 0) red[w] = s;
    __syncthreads();
    if (t == 0) {
        double tot = red[0] + red[1] + red[2] + red[3];
        out[OFF_PERP] = (float)exp(-tot);
        // loss = q_latent + 1.0*e_latent = 2*mean((c-z)^2)
        out[0] = (float)(loss_acc[0] * (2.0 / 33554432.0));
    }
}

extern "C" void kernel_launch(void* const* d_in, const int* in_sizes, int n_in,
                              void* d_out, int out_size, void* d_ws, size_t ws_size,
                              hipStream_t stream) {
    const float* X  = (const float*)d_in[0];
    const float* W1 = (const float*)d_in[1];
    const float* b1 = (const float*)d_in[2];
    const float* W2 = (const float*)d_in[3];
    const float* b2 = (const float*)d_in[4];
    const float* cb = (const float*)d_in[5];

    float* out = (float*)d_out;
    float* qz  = out + (size_t)OFF_Q;    // z, then quantized_st (in place)
    float* enc = out + (size_t)OFF_ENC;  // scratch: h64, then dist-lo, then one-hot
    float* nd  = out + (size_t)OFF_ND;   // -distances (hi part)
    double* h64 = (double*)enc;          // 8.4M doubles, 67MB < 268MB region
    float* ndlo = enc;

    double* zz = (double*)d_ws;          // [65536]
    double* cc = zz + 65536;             // [1024]
    double* loss_acc = cc + 1024;        // [1]
    int* counts = (int*)(loss_acc + 1);  // [1024]
    int* idx = counts + 1024;            // [65536]

    k_init<<<1, 256, 0, stream>>>(counts, loss_acc);
    k_gemm1<<<4096, 256, 0, stream>>>(X, W1, b1, h64);
    k_gemm2<<<8192, 256, 0, stream>>>(h64, W2, b2, qz, zz);
    k_ccnorm<<<1024, 64, 0, stream>>>(cb, cc);
    k_gemm3<<<32768, 256, 0, stream>>>(qz, cb, zz, cc, nd, ndlo);
    k_sample<<<32768, 256, 0, stream>>>(nd, ndlo, idx, counts);
    k_quant<<<8192, 256, 0, stream>>>(qz, cb, idx, loss_acc);
    k_zero_enc<<<2048, 256, 0, stream>>>(enc);
    k_scatter<<<256, 256, 0, stream>>>(enc, idx);
    k_scalars<<<1, 256, 0, stream>>>(counts, loss_acc, out);
}

// Round 2
// 1712.998 us; speedup vs baseline: 2.1988x; 2.1988x over previous
//
#include <hip/hip_runtime.h>
#include <stdint.h>

#define N_ROWS 65536
#define DIM 1024
#define HID 128
#define FD 512
#define KCB 1024
#define HALFCNT 33554432u

#define OFF_Q    1
#define OFF_PERP 33554433
#define OFF_ENC  33554434
#define OFF_ND   100663298

__device__ __forceinline__ uint32_t rotl32(uint32_t v, int r) { return (v << r) | (v >> (32 - r)); }

// JAX threefry2x32 with key (0, 42)
__device__ __forceinline__ void threefry(uint32_t c0, uint32_t c1, uint32_t& o0, uint32_t& o1) {
    const uint32_t ks0 = 0u, ks1 = 42u, ks2 = 0x1BD11BDAu ^ 0u ^ 42u;
    uint32_t x0 = c0 + ks0, x1 = c1 + ks1;
#define TFR(r) x0 += x1; x1 = rotl32(x1, r); x1 ^= x0;
    TFR(13) TFR(15) TFR(26) TFR(6)  x0 += ks1; x1 += ks2 + 1u;
    TFR(17) TFR(29) TFR(16) TFR(24) x0 += ks2; x1 += ks0 + 2u;
    TFR(13) TFR(15) TFR(26) TFR(6)  x0 += ks0; x1 += ks1 + 3u;
    TFR(17) TFR(29) TFR(16) TFR(24) x0 += ks1; x1 += ks2 + 4u;
    TFR(13) TFR(15) TFR(26) TFR(6)  x0 += ks2; x1 += ks0 + 5u;
#undef TFR
    o0 = x0; o1 = x1;
}

// JAX uniform->gumbel: u = max(FLT_MIN, bits-as-[1,2) - 1); g = -log(-log u). logf (libm) for
// relative accuracy near u->1 (v_log_f32 table is absolute-accurate -> 17% rel err there).
__device__ __forceinline__ float gumbel_f32(uint32_t b) {
    uint32_t m = b >> 9;
    float u = m ? (float)m * 1.1920928955078125e-07f : 1.17549435e-38f;
    return -logf(-logf(u));
}

__device__ __forceinline__ float fc(const float4& v, int i) { return ((const float*)&v)[i]; }

__global__ void k_init(int* __restrict__ counts, double* __restrict__ loss_acc) {
    int t = threadIdx.x;
    for (int k = t; k < KCB; k += 256) counts[k] = 0;
    if (t == 0) *loss_acc = 0.0;
}

// Fused MLP: z = relu(X@W1 + b1) @ W2 + b2, all f32. 32 rows/block; h stays in LDS.
__global__ __launch_bounds__(256) void k12(const float* __restrict__ X, const float* __restrict__ W1,
                                           const float* __restrict__ b1, const float* __restrict__ W2,
                                           const float* __restrict__ b2, float* __restrict__ z) {
    __shared__ float xs[32][36];      // 32 rows x 32 f (+4 pad, keeps 16B align, spreads banks)
    __shared__ float ws1[32 * 128];   // W1 chunk [32 j][128 c]
    __shared__ float hs[32][128];
    int t = threadIdx.x;
    int n0 = blockIdx.x * 32;
    // ---- phase A: h = relu(X@W1 + b1), per-thread 4 rows x 4 cols ----
    int c0 = (t & 31) * 4;
    int r0 = (t >> 5) * 4;
    float accA[4][4] = {};
    for (int j0 = 0; j0 < DIM; j0 += 32) {
        {   // stage xs: 256 float4 slots, 1/thread
            int r = t >> 3, f4 = t & 7;
            *(float4*)&xs[r][f4 * 4] = *(const float4*)&X[(size_t)(n0 + r) * DIM + j0 + f4 * 4];
        }
        #pragma unroll
        for (int u = 0; u < 4; ++u) {  // stage ws1: 1024 slots, 4/thread
            int s = t + 256 * u;
            int rw = s >> 5, c4 = s & 31;
            *(float4*)&ws1[rw * 128 + c4 * 4] = *(const float4*)&W1[(size_t)(j0 + rw) * HID + c4 * 4];
        }
        __syncthreads();
        #pragma unroll
        for (int j4 = 0; j4 < 32; j4 += 4) {
            float4 x4[4], w4[4];
            #pragma unroll
            for (int rr = 0; rr < 4; ++rr) x4[rr] = *(const float4*)&xs[r0 + rr][j4];
            #pragma unroll
            for (int jj = 0; jj < 4; ++jj) w4[jj] = *(const float4*)&ws1[(j4 + jj) * 128 + c0];
            #pragma unroll
            for (int rr = 0; rr < 4; ++rr)
                #pragma unroll
                for (int cc = 0; cc < 4; ++cc) {
                    float a = accA[rr][cc];
                    a = fmaf(x4[rr].x, fc(w4[0], cc), a);
                    a = fmaf(x4[rr].y, fc(w4[1], cc), a);
                    a = fmaf(x4[rr].z, fc(w4[2], cc), a);
                    a = fmaf(x4[rr].w, fc(w4[3], cc), a);
                    accA[rr][cc] = a;
                }
        }
        __syncthreads();
    }
    {
        float4 bb = *(const float4*)&b1[c0];
        #pragma unroll
        for (int rr = 0; rr < 4; ++rr) {
            float4 hv;
            hv.x = fmaxf(accA[rr][0] + bb.x, 0.f);
            hv.y = fmaxf(accA[rr][1] + bb.y, 0.f);
            hv.z = fmaxf(accA[rr][2] + bb.z, 0.f);
            hv.w = fmaxf(accA[rr][3] + bb.w, 0.f);
            *(float4*)&hs[r0 + rr][c0] = hv;
        }
    }
    __syncthreads();
    // ---- phase B: z = h@W2 + b2, per-thread 16 rows x 4 cols; W2 rows streamed from L2 ----
    int cb0 = (t & 127) * 4;
    int rb0 = (t >> 7) * 16;
    float accB[16][4] = {};
    for (int j4 = 0; j4 < HID; j4 += 4) {
        float4 w2v[4];
        #pragma unroll
        for (int jj = 0; jj < 4; ++jj) w2v[jj] = *(const float4*)&W2[(size_t)(j4 + jj) * FD + cb0];
        #pragma unroll
        for (int rr = 0; rr < 16; ++rr) {
            float4 h4 = *(const float4*)&hs[rb0 + rr][j4];  // wave-uniform address: broadcast
            #pragma unroll
            for (int cc = 0; cc < 4; ++cc) {
                float a = accB[rr][cc];
                a = fmaf(h4.x, fc(w2v[0], cc), a);
                a = fmaf(h4.y, fc(w2v[1], cc), a);
                a = fmaf(h4.z, fc(w2v[2], cc), a);
                a = fmaf(h4.w, fc(w2v[3], cc), a);
                accB[rr][cc] = a;
            }
        }
    }
    float4 b2v = *(const float4*)&b2[cb0];
    #pragma unroll
    for (int rr = 0; rr < 16; ++rr) {
        float4 zv;
        zv.x = accB[rr][0] + b2v.x;
        zv.y = accB[rr][1] + b2v.y;
        zv.z = accB[rr][2] + b2v.z;
        zv.w = accB[rr][3] + b2v.w;
        *(float4*)&z[(size_t)(n0 + rb0 + rr) * FD + cb0] = zv;
    }
}

// zz[n] = sum(z[n]^2) in f64 (output-precision only; drops out of argmax)
__global__ void k_zz(const float* __restrict__ z, double* __restrict__ zz) {
    int row = blockIdx.x * 4 + (threadIdx.x >> 6);
    int lane = threadIdx.x & 63;
    const float4* p = (const float4*)&z[(size_t)row * FD];
    float4 a = p[lane], b = p[lane + 64];
    double s = 0.0;
    s = fma((double)a.x, (double)a.x, s); s = fma((double)a.y, (double)a.y, s);
    s = fma((double)a.z, (double)a.z, s); s = fma((double)a.w, (double)a.w, s);
    s = fma((double)b.x, (double)b.x, s); s = fma((double)b.y, (double)b.y, s);
    s = fma((double)b.z, (double)b.z, s); s = fma((double)b.w, (double)b.w, s);
    for (int off = 32; off; off >>= 1) s += __shfl_down(s, off, 64);
    if (lane == 0) zz[row] = s;
}

__global__ void k_ccnorm(const float* __restrict__ cb, double* __restrict__ cc) {
    int k = blockIdx.x, lane = threadIdx.x;
    double s = 0.0;
    for (int f = lane; f < FD; f += 64) {
        double v = (double)cb[(size_t)k * FD + f];
        s = fma(v, v, s);
    }
    for (int off = 32; off; off >>= 1) s += __shfl_down(s, off, 64);
    if (lane == 0) cc[k] = s;
}

// f32 dot GEMM, 64n x 256k tile, 4x16 register tile; writes nd (output) and scr (sampling scores).
__global__ __launch_bounds__(256) void k_gemm3(const float* __restrict__ z, const float* __restrict__ cb,
                                               const double* __restrict__ zz, const double* __restrict__ cc,
                                               float* __restrict__ nd, float* __restrict__ scr) {
    __shared__ float zs[64 * 32];
    __shared__ float cs[256 * 32];
    int t = threadIdx.x;
    int bn = blockIdx.x >> 2;
    int bk = blockIdx.x & 3;
    int n0 = bn * 64, k0 = bk * 256;
    int tx = t & 15, ty = t >> 4;
    float acc[4][16] = {};
    for (int f0 = 0; f0 < FD; f0 += 32) {
        #pragma unroll
        for (int u = 0; u < 2; ++u) {      // zs: 512 float4 slots; fslot = fsrc ^ (row&7)
            int s = t + 256 * u;
            int r = s >> 3, fs = s & 7;
            int fsrc = fs ^ (r & 7);
            *(float4*)&zs[r * 32 + fs * 4] = *(const float4*)&z[(size_t)(n0 + r) * FD + f0 + fsrc * 4];
        }
        #pragma unroll
        for (int u = 0; u < 8; ++u) {      // cs: 2048 slots
            int s = t + 256 * u;
            int r = s >> 3, fs = s & 7;
            int fsrc = fs ^ (r & 7);
            *(float4*)&cs[r * 32 + fs * 4] = *(const float4*)&cb[(size_t)(k0 + r) * FD + f0 + fsrc * 4];
        }
        __syncthreads();
        #pragma unroll
        for (int jj = 0; jj < 8; ++jj) {
            float4 z4[4];
            #pragma unroll
            for (int i = 0; i < 4; ++i) {
                int row = ty * 4 + i;
                z4[i] = *(const float4*)&zs[row * 32 + (jj ^ (row & 7)) * 4];
            }
            #pragma unroll
            for (int q = 0; q < 16; ++q) {
                int row = tx + 16 * q;
                float4 c4 = *(const float4*)&cs[row * 32 + (jj ^ (row & 7)) * 4];
                #pragma unroll
                for (int i = 0; i < 4; ++i) {
                    float a = acc[i][q];
                    a = fmaf(z4[i].x, c4.x, a);
                    a = fmaf(z4[i].y, c4.y, a);
                    a = fmaf(z4[i].z, c4.z, a);
                    a = fmaf(z4[i].w, c4.w, a);
                    acc[i][q] = a;
                }
            }
        }
        __syncthreads();
    }
    #pragma unroll
    for (int i = 0; i < 4; ++i) {
        int n = n0 + ty * 4 + i;
        double zn = zz[n];
        #pragma unroll
        for (int q = 0; q < 16; ++q) {
            int k = k0 + tx + 16 * q;
            double dot2 = 2.0 * (double)acc[i][q];
            double ccv = cc[k];
            nd[(size_t)n * KCB + k]  = (float)(dot2 - zn - ccv);
            scr[(size_t)n * KCB + k] = (float)((dot2 - ccv) * 10.0);   // zz is per-row const: argmax-invariant
        }
    }
}

// Rows n and n+32768 share threefry counters (JAX even-split). Argmax of scr + gumbel, all f32.
__global__ __launch_bounds__(256) void k_sample(const float* __restrict__ scr,
                                                int* __restrict__ idx, int* __restrict__ counts) {
    int n = blockIdx.x;
    int t = threadIdx.x;
    float best0 = -1e30f, best1 = -1e30f;
    int bi0 = 0, bi1 = 0;
    for (int k = t; k < KCB; k += 256) {
        uint32_t ctr = (uint32_t)(n * KCB + k);
        uint32_t r0, r1;
        threefry(ctr, ctr + HALFCNT, r0, r1);
        float g0 = gumbel_f32(r0), g1 = gumbel_f32(r1);
        float s0 = scr[(size_t)n * KCB + k] + g0;
        float s1 = scr[(size_t)(n + 32768) * KCB + k] + g1;
        if (s0 > best0) { best0 = s0; bi0 = k; }
        if (s1 > best1) { best1 = s1; bi1 = k; }
    }
    __shared__ float sv0[256], sv1[256];
    __shared__ int si0[256], si1[256];
    sv0[t] = best0; si0[t] = bi0; sv1[t] = best1; si1[t] = bi1;
    __syncthreads();
    for (int off = 128; off; off >>= 1) {
        if (t < off) {
            if (sv0[t + off] > sv0[t] || (sv0[t + off] == sv0[t] && si0[t + off] < si0[t])) {
                sv0[t] = sv0[t + off]; si0[t] = si0[t + off];
            }
            if (sv1[t + off] > sv1[t] || (sv1[t + off] == sv1[t] && si1[t + off] < si1[t])) {
                sv1[t] = sv1[t + off]; si1[t] = si1[t + off];
            }
        }
        __syncthreads();
    }
    if (t == 0) {
        idx[n] = si0[0];
        idx[n + 32768] = si1[0];
        atomicAdd(&counts[si0[0]], 1);
        atomicAdd(&counts[si1[0]], 1);
    }
}

// In-place: q_st = z + (c[idx]-z) (f32, JAX order), and f64 loss accumulation of (c-z)^2.
__global__ __launch_bounds__(256) void k_quant(float* __restrict__ qz, const float* __restrict__ cb,
                                               const int* __restrict__ idx, double* __restrict__ loss_acc) {
    size_t tid = (size_t)blockIdx.x * 256 + threadIdx.x;
    size_t stride = (size_t)gridDim.x * 256;
    double local = 0.0;
    for (size_t ii = tid; ii < (size_t)N_ROWS * FD; ii += stride) {
        int n = (int)(ii >> 9);
        int f = (int)(ii & 511);
        float zv = qz[ii];
        float cv = cb[(size_t)idx[n] * FD + f];
        float d1 = cv - zv;
        qz[ii] = zv + d1;
        double dd = (double)cv - (double)zv;
        local = fma(dd, dd, local);
    }
    for (int off = 32; off; off >>= 1) local += __shfl_down(local, off, 64);
    __shared__ double red[4];
    int lane = threadIdx.x & 63, w = threadIdx.x >> 6;
    if (lane == 0) red[w] = local;
    __syncthreads();
    if (threadIdx.x == 0) atomicAdd(loss_acc, red[0] + red[1] + red[2] + red[3]);
}

__global__ void k_zero_enc(float* __restrict__ enc) {
    size_t i = (size_t)blockIdx.x * blockDim.x + threadIdx.x;
    size_t stride = (size_t)gridDim.x * blockDim.x;
    float2* p = (float2*)enc;
    size_t n2 = (size_t)N_ROWS * KCB / 2;
    float2 zv = make_float2(0.f, 0.f);
    for (size_t j = i; j < n2; j += stride) p[j] = zv;
}

__global__ void k_scatter(float* __restrict__ enc, const int* __restrict__ idx) {
    int n = blockIdx.x * 256 + threadIdx.x;
    enc[(size_t)n * KCB + idx[n]] = 1.0f;
}

__global__ void k_scalars(const int* __restrict__ counts, const double* __restrict__ loss_acc,
                          float* __restrict__ out) {
    int t = threadIdx.x;
    double s = 0.0;
    for (int k = t; k < KCB; k += 256) {
        double p = (double)counts[k] * (1.0 / 65536.0);
        s += p * log(p + 1e-10);
    }
    for (int off = 32; off; off >>= 1) s += __shfl_down(s, off, 64);
    __shared__ double red[4];
    int lane = t & 63, w = t >> 6;
    if (lane == 0) red[w] = s;
    __syncthreads();
    if (t == 0) {
        double tot = red[0] + red[1] + red[2] + red[3];
        out[OFF_PERP] = (float)exp(-tot);
        out[0] = (float)(loss_acc[0] * (2.0 / 33554432.0));
    }
}

extern "C" void kernel_launch(void* const* d_in, const int* in_sizes, int n_in,
                              void* d_out, int out_size, void* d_ws, size_t ws_size,
                              hipStream_t stream) {
    const float* X  = (const float*)d_in[0];
    const float* W1 = (const float*)d_in[1];
    const float* b1 = (const float*)d_in[2];
    const float* W2 = (const float*)d_in[3];
    const float* b2 = (const float*)d_in[4];
    const float* cb = (const float*)d_in[5];

    float* out = (float*)d_out;
    float* qz  = out + (size_t)OFF_Q;    // z, then quantized_st (in place)
    float* enc = out + (size_t)OFF_ENC;  // scratch: scr (sampling scores), then one-hot
    float* nd  = out + (size_t)OFF_ND;   // -distances output
    float* scr = enc;

    double* zz = (double*)d_ws;          // [65536]
    double* cc = zz + 65536;             // [1024]
    double* loss_acc = cc + 1024;        // [1]
    int* counts = (int*)(loss_acc + 1);  // [1024]
    int* idx = counts + 1024;            // [65536]

    k_init<<<1, 256, 0, stream>>>(counts, loss_acc);
    k12<<<2048, 256, 0, stream>>>(X, W1, b1, W2, b2, qz);
    k_zz<<<16384, 256, 0, stream>>>(qz, zz);
    k_ccnorm<<<1024, 64, 0, stream>>>(cb, cc);
    k_gemm3<<<4096, 256, 0, stream>>>(qz, cb, zz, cc, nd, scr);
    k_sample<<<32768, 256, 0, stream>>>(scr, idx, counts);
    k_quant<<<8192, 256, 0, stream>>>(qz, cb, idx, loss_acc);
    k_zero_enc<<<2048, 256, 0, stream>>>(enc);
    k_scatter<<<256, 256, 0, stream>>>(enc, idx);
    k_scalars<<<1, 256, 0, stream>>>(counts, loss_acc, out);
}

// Round 3
// 1003.819 us; speedup vs baseline: 3.7522x; 1.7065x over previous
//
#include <hip/hip_runtime.h>
#include <stdint.h>

#define N_ROWS 65536
#define DIM 1024
#define HID 128
#define FD 512
#define KCB 1024
#define HALFCNT 33554432u

#define OFF_Q    1
#define OFF_PERP 33554433
#define OFF_ENC  33554434
#define OFF_ND   100663298

typedef __attribute__((ext_vector_type(8))) short sh8;     // 8 bf16 in 4 VGPRs
typedef __attribute__((ext_vector_type(4))) float f32x4;

__device__ __forceinline__ uint32_t rotl32(uint32_t v, int r) { return (v << r) | (v >> (32 - r)); }

// JAX threefry2x32 with key (0, 42)
__device__ __forceinline__ void threefry(uint32_t c0, uint32_t c1, uint32_t& o0, uint32_t& o1) {
    const uint32_t ks0 = 0u, ks1 = 42u, ks2 = 0x1BD11BDAu ^ 0u ^ 42u;
    uint32_t x0 = c0 + ks0, x1 = c1 + ks1;
#define TFR(r) x0 += x1; x1 = rotl32(x1, r); x1 ^= x0;
    TFR(13) TFR(15) TFR(26) TFR(6)  x0 += ks1; x1 += ks2 + 1u;
    TFR(17) TFR(29) TFR(16) TFR(24) x0 += ks2; x1 += ks0 + 2u;
    TFR(13) TFR(15) TFR(26) TFR(6)  x0 += ks0; x1 += ks1 + 3u;
    TFR(17) TFR(29) TFR(16) TFR(24) x0 += ks1; x1 += ks2 + 4u;
    TFR(13) TFR(15) TFR(26) TFR(6)  x0 += ks2; x1 += ks0 + 5u;
#undef TFR
    o0 = x0; o1 = x1;
}

__device__ __forceinline__ float gumbel_f32(uint32_t b) {
    uint32_t m = b >> 9;
    float u = m ? (float)m * 1.1920928955078125e-07f : 1.17549435e-38f;
    return -logf(-logf(u));
}

__device__ __forceinline__ float fc(const float4& v, int i) { return ((const float*)&v)[i]; }

__device__ __forceinline__ ushort bf16rne(float f) {
    uint32_t u = __float_as_uint(f);
    return (ushort)((u + 0x7FFFu + ((u >> 16) & 1u)) >> 16);
}
__device__ __forceinline__ void split2(float v, ushort& h, ushort& l) {
    h = bf16rne(v);
    float hf = __uint_as_float(((uint32_t)h) << 16);
    l = bf16rne(v - hf);
}

// async global->LDS, 16B per lane; LDS dest = wave-uniform base + lane*16
__device__ __forceinline__ void async_cp16(const void* g, void* l) {
    __builtin_amdgcn_global_load_lds(
        (const __attribute__((address_space(1))) void*)g,
        (__attribute__((address_space(3))) void*)l, 16, 0, 0);
}

__global__ void k_init(int* __restrict__ counts, double* __restrict__ loss_acc) {
    int t = threadIdx.x;
    for (int k = t; k < KCB; k += 256) counts[k] = 0;
    if (t == 0) *loss_acc = 0.0;
}

// codebook prep: bf16 hi/lo split + f64 row norms. 1 block per codebook row, 64 lanes.
__global__ void k_cbprep(const float* __restrict__ cb, ushort* __restrict__ cbh,
                         ushort* __restrict__ cbl, double* __restrict__ cc) {
    int k = blockIdx.x, l = threadIdx.x;
    const float4* row = (const float4*)(cb + (size_t)k * FD);
    float4 a = row[l * 2], b = row[l * 2 + 1];
    float v[8] = {a.x, a.y, a.z, a.w, b.x, b.y, b.z, b.w};
    ushort hh[8], ll[8];
    double s = 0.0;
    #pragma unroll
    for (int e = 0; e < 8; ++e) {
        split2(v[e], hh[e], ll[e]);
        s = fma((double)v[e], (double)v[e], s);
    }
    uint4 hv, lv;
    hv.x = (uint32_t)hh[0] | ((uint32_t)hh[1] << 16); hv.y = (uint32_t)hh[2] | ((uint32_t)hh[3] << 16);
    hv.z = (uint32_t)hh[4] | ((uint32_t)hh[5] << 16); hv.w = (uint32_t)hh[6] | ((uint32_t)hh[7] << 16);
    lv.x = (uint32_t)ll[0] | ((uint32_t)ll[1] << 16); lv.y = (uint32_t)ll[2] | ((uint32_t)ll[3] << 16);
    lv.z = (uint32_t)ll[4] | ((uint32_t)ll[5] << 16); lv.w = (uint32_t)ll[6] | ((uint32_t)ll[7] << 16);
    *(uint4*)(cbh + (size_t)k * FD + l * 8) = hv;
    *(uint4*)(cbl + (size_t)k * FD + l * 8) = lv;
    for (int off = 32; off; off >>= 1) s += __shfl_down(s, off, 64);
    if (l == 0) cc[k] = s;
}

// Fused MLP: z = relu(X@W1+b1)@W2+b2 (f32) + epilogue: bf16 hi/lo of z, and zz row norms (f32).
__global__ __launch_bounds__(256) void k12(const float* __restrict__ X, const float* __restrict__ W1,
                                           const float* __restrict__ b1, const float* __restrict__ W2,
                                           const float* __restrict__ b2, float* __restrict__ z,
                                           ushort* __restrict__ zbh, ushort* __restrict__ zbl,
                                           float* __restrict__ zz) {
    __shared__ float xs[32][36];
    __shared__ float ws1[32 * 128];
    __shared__ float hs[32][128];
    __shared__ float zzr[4][16];
    int t = threadIdx.x;
    int n0 = blockIdx.x * 32;
    int c0 = (t & 31) * 4;
    int r0 = (t >> 5) * 4;
    float accA[4][4] = {};
    for (int j0 = 0; j0 < DIM; j0 += 32) {
        {
            int r = t >> 3, f4 = t & 7;
            *(float4*)&xs[r][f4 * 4] = *(const float4*)&X[(size_t)(n0 + r) * DIM + j0 + f4 * 4];
        }
        #pragma unroll
        for (int u = 0; u < 4; ++u) {
            int s = t + 256 * u;
            int rw = s >> 5, c4 = s & 31;
            *(float4*)&ws1[rw * 128 + c4 * 4] = *(const float4*)&W1[(size_t)(j0 + rw) * HID + c4 * 4];
        }
        __syncthreads();
        #pragma unroll
        for (int j4 = 0; j4 < 32; j4 += 4) {
            float4 x4[4], w4[4];
            #pragma unroll
            for (int rr = 0; rr < 4; ++rr) x4[rr] = *(const float4*)&xs[r0 + rr][j4];
            #pragma unroll
            for (int jj = 0; jj < 4; ++jj) w4[jj] = *(const float4*)&ws1[(j4 + jj) * 128 + c0];
            #pragma unroll
            for (int rr = 0; rr < 4; ++rr)
                #pragma unroll
                for (int cc2 = 0; cc2 < 4; ++cc2) {
                    float a = accA[rr][cc2];
                    a = fmaf(x4[rr].x, fc(w4[0], cc2), a);
                    a = fmaf(x4[rr].y, fc(w4[1], cc2), a);
                    a = fmaf(x4[rr].z, fc(w4[2], cc2), a);
                    a = fmaf(x4[rr].w, fc(w4[3], cc2), a);
                    accA[rr][cc2] = a;
                }
        }
        __syncthreads();
    }
    {
        float4 bb = *(const float4*)&b1[c0];
        #pragma unroll
        for (int rr = 0; rr < 4; ++rr) {
            float4 hv;
            hv.x = fmaxf(accA[rr][0] + bb.x, 0.f);
            hv.y = fmaxf(accA[rr][1] + bb.y, 0.f);
            hv.z = fmaxf(accA[rr][2] + bb.z, 0.f);
            hv.w = fmaxf(accA[rr][3] + bb.w, 0.f);
            *(float4*)&hs[r0 + rr][c0] = hv;
        }
    }
    __syncthreads();
    int cb0 = (t & 127) * 4;
    int rb0 = (t >> 7) * 16;
    float accB[16][4] = {};
    for (int j4 = 0; j4 < HID; j4 += 4) {
        float4 w2v[4];
        #pragma unroll
        for (int jj = 0; jj < 4; ++jj) w2v[jj] = *(const float4*)&W2[(size_t)(j4 + jj) * FD + cb0];
        #pragma unroll
        for (int rr = 0; rr < 16; ++rr) {
            float4 h4 = *(const float4*)&hs[rb0 + rr][j4];
            #pragma unroll
            for (int cc2 = 0; cc2 < 4; ++cc2) {
                float a = accB[rr][cc2];
                a = fmaf(h4.x, fc(w2v[0], cc2), a);
                a = fmaf(h4.y, fc(w2v[1], cc2), a);
                a = fmaf(h4.z, fc(w2v[2], cc2), a);
                a = fmaf(h4.w, fc(w2v[3], cc2), a);
                accB[rr][cc2] = a;
            }
        }
    }
    float4 b2v = *(const float4*)&b2[cb0];
    float rsq[16];
    #pragma unroll
    for (int rr = 0; rr < 16; ++rr) {
        float4 zv;
        zv.x = accB[rr][0] + b2v.x;
        zv.y = accB[rr][1] + b2v.y;
        zv.z = accB[rr][2] + b2v.z;
        zv.w = accB[rr][3] + b2v.w;
        size_t rowb = (size_t)(n0 + rb0 + rr) * FD + cb0;
        *(float4*)&z[rowb] = zv;
        ushort h[4], l[4];
        split2(zv.x, h[0], l[0]); split2(zv.y, h[1], l[1]);
        split2(zv.z, h[2], l[2]); split2(zv.w, h[3], l[3]);
        uint2 hp, lp;
        hp.x = (uint32_t)h[0] | ((uint32_t)h[1] << 16); hp.y = (uint32_t)h[2] | ((uint32_t)h[3] << 16);
        lp.x = (uint32_t)l[0] | ((uint32_t)l[1] << 16); lp.y = (uint32_t)l[2] | ((uint32_t)l[3] << 16);
        *(uint2*)&zbh[rowb] = hp;
        *(uint2*)&zbl[rowb] = lp;
        rsq[rr] = zv.x * zv.x + zv.y * zv.y + zv.z * zv.z + zv.w * zv.w;
    }
    int lane = t & 63, w = t >> 6;
    #pragma unroll
    for (int rr = 0; rr < 16; ++rr)
        for (int off = 32; off; off >>= 1) rsq[rr] += __shfl_down(rsq[rr], off, 64);
    if (lane == 0)
        #pragma unroll
        for (int rr = 0; rr < 16; ++rr) zzr[w][rr] = rsq[rr];
    __syncthreads();
    if (t < 32) {
        int g = t >> 4, rr = t & 15;
        zz[n0 + g * 16 + rr] = zzr[2 * g][rr] + zzr[2 * g + 1][rr];
    }
}

// Distance GEMM via split-bf16 MFMA: dot = zh*ch + zh*cl + zl*ch (f32 acc).
// 128x128 tile, 4 waves (2x2), BK=64, global_load_lds staging with pre-swizzled source.
__global__ __launch_bounds__(256) void k_mfma3(const ushort* __restrict__ zbh, const ushort* __restrict__ zbl,
                                               const ushort* __restrict__ cbh, const ushort* __restrict__ cbl,
                                               const float* __restrict__ zz, const double* __restrict__ cc,
                                               float* __restrict__ nd) {
    __shared__ __align__(16) char lds[65536];   // Ah | Al | Bh | Bl, 16 KB each
    int t = threadIdx.x;
    int lane = t & 63, w = t >> 6;
    int wr = w >> 1, wc = w & 1;
    int bid = blockIdx.x;
    int bm = ((bid >> 6) << 3) | (bid & 7);   // XCD-bijective: 8 n-tiles of a row-panel share an XCD
    int bkn = (bid >> 3) & 7;
    const ushort* Ahg = zbh + (size_t)bm * 128 * FD;
    const ushort* Alg = zbl + (size_t)bm * 128 * FD;
    const ushort* Bhg = cbh + (size_t)bkn * 128 * FD;
    const ushort* Blg = cbl + (size_t)bkn * 128 * FD;

    f32x4 zero4 = {0.f, 0.f, 0.f, 0.f};
    f32x4 acc[4][4];
    #pragma unroll
    for (int i = 0; i < 4; ++i)
        #pragma unroll
        for (int j = 0; j < 4; ++j) acc[i][j] = zero4;

    for (int k0 = 0; k0 < FD; k0 += 64) {
        // stage: each wave stages rows [w*32, w*32+32) of each buffer; 8 rows (1KB) per instr.
        #pragma unroll
        for (int i = 0; i < 4; ++i) {
            int rr = w * 32 + i * 8;
            int row = rr + (lane >> 3);
            int csrc = (lane & 7) ^ (row & 7);
            size_t goff = (size_t)row * FD + k0 + csrc * 8;
            async_cp16(Ahg + goff, lds + rr * 128);
            async_cp16(Alg + goff, lds + 16384 + rr * 128);
            async_cp16(Bhg + goff, lds + 32768 + rr * 128);
            async_cp16(Blg + goff, lds + 49152 + rr * 128);
        }
        __syncthreads();
        #pragma unroll
        for (int kh = 0; kh < 2; ++kh) {
            int ch = kh * 4 + (lane >> 4);
            sh8 ah[4], al[4], bh[4], bl[4];
            #pragma unroll
            for (int i = 0; i < 4; ++i) {
                int ra = wr * 64 + i * 16 + (lane & 15);
                int off = ra * 128 + ((ch ^ (ra & 7)) << 4);
                ah[i] = *(const sh8*)(lds + off);
                al[i] = *(const sh8*)(lds + 16384 + off);
            }
            #pragma unroll
            for (int j = 0; j < 4; ++j) {
                int rb = wc * 64 + j * 16 + (lane & 15);
                int off = rb * 128 + ((ch ^ (rb & 7)) << 4);
                bh[j] = *(const sh8*)(lds + 32768 + off);
                bl[j] = *(const sh8*)(lds + 49152 + off);
            }
            #pragma unroll
            for (int i = 0; i < 4; ++i)
                #pragma unroll
                for (int j = 0; j < 4; ++j) {
                    acc[i][j] = __builtin_amdgcn_mfma_f32_16x16x32_bf16(ah[i], bh[j], acc[i][j], 0, 0, 0);
                    acc[i][j] = __builtin_amdgcn_mfma_f32_16x16x32_bf16(ah[i], bl[j], acc[i][j], 0, 0, 0);
                    acc[i][j] = __builtin_amdgcn_mfma_f32_16x16x32_bf16(al[i], bh[j], acc[i][j], 0, 0, 0);
                }
        }
        __syncthreads();
    }
    // epilogue: nd = 2*dot - zz[row] - cc[col]; D layout: col=lane&15, row=(lane>>4)*4+reg
    int lane15 = lane & 15, lg = lane >> 4;
    int gcol[4];
    double ccv[4];
    #pragma unroll
    for (int j = 0; j < 4; ++j) {
        gcol[j] = bkn * 128 + wc * 64 + j * 16 + lane15;
        ccv[j] = cc[gcol[j]];
    }
    #pragma unroll
    for (int i = 0; i < 4; ++i)
        #pragma unroll
        for (int r = 0; r < 4; ++r) {
            int grow = bm * 128 + wr * 64 + i * 16 + lg * 4 + r;
            double zv = (double)zz[grow];
            size_t rowoff = (size_t)grow << 10;
            #pragma unroll
            for (int j = 0; j < 4; ++j)
                nd[rowoff + gcol[j]] = (float)(2.0 * (double)acc[i][j][r] - zv - ccv[j]);
        }
}

// Argmax of nd/TEMP + gumbel; zz[n] is row-constant (argmax-invariant) but restores scr scale.
__global__ __launch_bounds__(256) void k_sample(const float* __restrict__ nd, const float* __restrict__ zz,
                                                int* __restrict__ idx, int* __restrict__ counts) {
    int n = blockIdx.x;
    int t = threadIdx.x;
    float zzn0 = zz[n], zzn1 = zz[n + 32768];
    float best0 = -1e30f, best1 = -1e30f;
    int bi0 = 0, bi1 = 0;
    for (int k = t; k < KCB; k += 256) {
        uint32_t ctr = (uint32_t)(n * KCB + k);
        uint32_t r0, r1;
        threefry(ctr, ctr + HALFCNT, r0, r1);
        float g0 = gumbel_f32(r0), g1 = gumbel_f32(r1);
        float s0 = (nd[(size_t)n * KCB + k] + zzn0) * 10.0f + g0;
        float s1 = (nd[(size_t)(n + 32768) * KCB + k] + zzn1) * 10.0f + g1;
        if (s0 > best0) { best0 = s0; bi0 = k; }
        if (s1 > best1) { best1 = s1; bi1 = k; }
    }
    __shared__ float sv0[256], sv1[256];
    __shared__ int si0[256], si1[256];
    sv0[t] = best0; si0[t] = bi0; sv1[t] = best1; si1[t] = bi1;
    __syncthreads();
    for (int off = 128; off; off >>= 1) {
        if (t < off) {
            if (sv0[t + off] > sv0[t] || (sv0[t + off] == sv0[t] && si0[t + off] < si0[t])) {
                sv0[t] = sv0[t + off]; si0[t] = si0[t + off];
            }
            if (sv1[t + off] > sv1[t] || (sv1[t + off] == sv1[t] && si1[t + off] < si1[t])) {
                sv1[t] = sv1[t + off]; si1[t] = si1[t + off];
            }
        }
        __syncthreads();
    }
    if (t == 0) {
        idx[n] = si0[0];
        idx[n + 32768] = si1[0];
        atomicAdd(&counts[si0[0]], 1);
        atomicAdd(&counts[si1[0]], 1);
    }
}

__global__ __launch_bounds__(256) void k_quant(float* __restrict__ qz, const float* __restrict__ cb,
                                               const int* __restrict__ idx, double* __restrict__ loss_acc) {
    size_t tid = (size_t)blockIdx.x * 256 + threadIdx.x;
    size_t stride = (size_t)gridDim.x * 256;
    double local = 0.0;
    for (size_t ii = tid; ii < (size_t)N_ROWS * FD; ii += stride) {
        int n = (int)(ii >> 9);
        int f = (int)(ii & 511);
        float zv = qz[ii];
        float cv = cb[(size_t)idx[n] * FD + f];
        float d1 = cv - zv;
        qz[ii] = zv + d1;
        double dd = (double)cv - (double)zv;
        local = fma(dd, dd, local);
    }
    for (int off = 32; off; off >>= 1) local += __shfl_down(local, off, 64);
    __shared__ double red[4];
    int lane = threadIdx.x & 63, w = threadIdx.x >> 6;
    if (lane == 0) red[w] = local;
    __syncthreads();
    if (threadIdx.x == 0) atomicAdd(loss_acc, red[0] + red[1] + red[2] + red[3]);
}

__global__ void k_zero_enc(float* __restrict__ enc) {
    size_t i = (size_t)blockIdx.x * blockDim.x + threadIdx.x;
    size_t stride = (size_t)gridDim.x * blockDim.x;
    float2* p = (float2*)enc;
    size_t n2 = (size_t)N_ROWS * KCB / 2;
    float2 zv = make_float2(0.f, 0.f);
    for (size_t j = i; j < n2; j += stride) p[j] = zv;
}

__global__ void k_scatter(float* __restrict__ enc, const int* __restrict__ idx) {
    int n = blockIdx.x * 256 + threadIdx.x;
    enc[(size_t)n * KCB + idx[n]] = 1.0f;
}

__global__ void k_scalars(const int* __restrict__ counts, const double* __restrict__ loss_acc,
                          float* __restrict__ out) {
    int t = threadIdx.x;
    double s = 0.0;
    for (int k = t; k < KCB; k += 256) {
        double p = (double)counts[k] * (1.0 / 65536.0);
        s += p * log(p + 1e-10);
    }
    for (int off = 32; off; off >>= 1) s += __shfl_down(s, off, 64);
    __shared__ double red[4];
    int lane = t & 63, w = t >> 6;
    if (lane == 0) red[w] = s;
    __syncthreads();
    if (t == 0) {
        double tot = red[0] + red[1] + red[2] + red[3];
        out[OFF_PERP] = (float)exp(-tot);
        out[0] = (float)(loss_acc[0] * (2.0 / 33554432.0));
    }
}

extern "C" void kernel_launch(void* const* d_in, const int* in_sizes, int n_in,
                              void* d_out, int out_size, void* d_ws, size_t ws_size,
                              hipStream_t stream) {
    const float* X  = (const float*)d_in[0];
    const float* W1 = (const float*)d_in[1];
    const float* b1 = (const float*)d_in[2];
    const float* W2 = (const float*)d_in[3];
    const float* b2 = (const float*)d_in[4];
    const float* cb = (const float*)d_in[5];

    float* out = (float*)d_out;
    float* qz  = out + (size_t)OFF_Q;    // z, then quantized_st (in place)
    float* enc = out + (size_t)OFF_ENC;  // scratch: zbh/zbl/cbh/cbl, then one-hot
    float* nd  = out + (size_t)OFF_ND;   // -distances output

    // bf16 split buffers in enc region, padded +2 floats for 16B alignment
    ushort* zbh = (ushort*)(enc + 2);       // [65536*512]
    ushort* zbl = zbh + (size_t)N_ROWS * FD;
    ushort* cbh = zbl + (size_t)N_ROWS * FD;
    ushort* cbl = cbh + (size_t)KCB * FD;

    float* zz = (float*)d_ws;            // [65536] f32
    double* cc = (double*)(zz + 65536);  // [1024]
    double* loss_acc = cc + 1024;        // [1]
    int* counts = (int*)(loss_acc + 1);  // [1024]
    int* idx = counts + 1024;            // [65536]

    k_init<<<1, 256, 0, stream>>>(counts, loss_acc);
    k_cbprep<<<1024, 64, 0, stream>>>(cb, cbh, cbl, cc);
    k12<<<2048, 256, 0, stream>>>(X, W1, b1, W2, b2, qz, zbh, zbl, zz);
    k_mfma3<<<4096, 256, 0, stream>>>(zbh, zbl, cbh, cbl, zz, cc, nd);
    k_sample<<<32768, 256, 0, stream>>>(nd, zz, idx, counts);
    k_quant<<<8192, 256, 0, stream>>>(qz, cb, idx, loss_acc);
    k_zero_enc<<<2048, 256, 0, stream>>>(enc);
    k_scatter<<<256, 256, 0, stream>>>(enc, idx);
    k_scalars<<<1, 256, 0, stream>>>(counts, loss_acc, out);
}

// Round 4
// 738.014 us; speedup vs baseline: 5.1036x; 1.3602x over previous
//
#include <hip/hip_runtime.h>
#include <stdint.h>

#define N_ROWS 65536
#define DIM 1024
#define HID 128
#define FD 512
#define KCB 1024
#define HALFCNT 33554432u

#define OFF_Q    1
#define OFF_PERP 33554433
#define OFF_ENC  33554434
#define OFF_ND   100663298

typedef __attribute__((ext_vector_type(8))) short sh8;     // 8 bf16 in 4 VGPRs
typedef __attribute__((ext_vector_type(4))) float f32x4;

__device__ __forceinline__ uint32_t rotl32(uint32_t v, int r) { return (v << r) | (v >> (32 - r)); }

// JAX threefry2x32 with key (0, 42)
__device__ __forceinline__ void threefry(uint32_t c0, uint32_t c1, uint32_t& o0, uint32_t& o1) {
    const uint32_t ks0 = 0u, ks1 = 42u, ks2 = 0x1BD11BDAu ^ 0u ^ 42u;
    uint32_t x0 = c0 + ks0, x1 = c1 + ks1;
#define TFR(r) x0 += x1; x1 = rotl32(x1, r); x1 ^= x0;
    TFR(13) TFR(15) TFR(26) TFR(6)  x0 += ks1; x1 += ks2 + 1u;
    TFR(17) TFR(29) TFR(16) TFR(24) x0 += ks2; x1 += ks0 + 2u;
    TFR(13) TFR(15) TFR(26) TFR(6)  x0 += ks0; x1 += ks1 + 3u;
    TFR(17) TFR(29) TFR(16) TFR(24) x0 += ks1; x1 += ks2 + 4u;
    TFR(13) TFR(15) TFR(26) TFR(6)  x0 += ks2; x1 += ks0 + 5u;
#undef TFR
    o0 = x0; o1 = x1;
}

__device__ __forceinline__ float gumbel_f32(uint32_t b) {
    uint32_t m = b >> 9;
    float u = m ? (float)m * 1.1920928955078125e-07f : 1.17549435e-38f;
    return -logf(-logf(u));
}

__device__ __forceinline__ ushort bf16rne(float f) {
    uint32_t u = __float_as_uint(f);
    return (ushort)((u + 0x7FFFu + ((u >> 16) & 1u)) >> 16);
}
// trunc-hi split: h = bit-truncate, l = RNE(v - h). |l| <= 2^-8 |v|; dropped lo*lo in 3-product
// MFMA is ~2^-16 rel -> logit error ~1e-5: negligible vs gumbel margins.
__device__ __forceinline__ void split2t(float v, ushort& h, ushort& l) {
    uint32_t u = __float_as_uint(v);
    h = (ushort)(u >> 16);
    float hf = __uint_as_float(u & 0xFFFF0000u);
    l = bf16rne(v - hf);
}

// async global->LDS, 16B per lane; LDS dest = wave-uniform base + lane*16
__device__ __forceinline__ void async_cp16(const void* g, void* l) {
    __builtin_amdgcn_global_load_lds(
        (const __attribute__((address_space(1))) void*)g,
        (__attribute__((address_space(3))) void*)l, 16, 0, 0);
}

__global__ void k_init(int* __restrict__ counts, double* __restrict__ lossb) {
    int t = threadIdx.x;
    for (int k = t; k < KCB; k += 256) counts[k] = 0;
    if (t < 256) lossb[t] = 0.0;
}

// codebook prep: bf16 hi/lo split + f64 row norms
__global__ void k_cbprep(const float* __restrict__ cb, ushort* __restrict__ cbh,
                         ushort* __restrict__ cbl, double* __restrict__ cc) {
    int k = blockIdx.x, l = threadIdx.x;
    const float4* row = (const float4*)(cb + (size_t)k * FD);
    float4 a = row[l * 2], b = row[l * 2 + 1];
    float v[8] = {a.x, a.y, a.z, a.w, b.x, b.y, b.z, b.w};
    uint32_t hu[4], lu[4];
    double s = 0.0;
    #pragma unroll
    for (int e = 0; e < 4; ++e) {
        ushort h0, l0, h1, l1;
        split2t(v[2 * e], h0, l0);
        split2t(v[2 * e + 1], h1, l1);
        hu[e] = (uint32_t)h0 | ((uint32_t)h1 << 16);
        lu[e] = (uint32_t)l0 | ((uint32_t)l1 << 16);
        s = fma((double)v[2 * e], (double)v[2 * e], s);
        s = fma((double)v[2 * e + 1], (double)v[2 * e + 1], s);
    }
    *(uint4*)(cbh + (size_t)k * FD + l * 8) = make_uint4(hu[0], hu[1], hu[2], hu[3]);
    *(uint4*)(cbl + (size_t)k * FD + l * 8) = make_uint4(lu[0], lu[1], lu[2], lu[3]);
    for (int off = 32; off; off >>= 1) s += __shfl_down(s, off, 64);
    if (l == 0) cc[k] = s;
}

// W1 [1024][128] -> transposed split w1th/w1tl [128 col][1024 k] bf16
__global__ void k_w1prep(const float* __restrict__ W1, ushort* __restrict__ w1th, ushort* __restrict__ w1tl) {
    int c = blockIdx.x;
    int t = threadIdx.x;
    #pragma unroll
    for (int u = 0; u < 4; ++u) {
        int k = t + u * 256;
        float v = W1[(size_t)k * HID + c];
        ushort h, l;
        split2t(v, h, l);
        w1th[(size_t)c * DIM + k] = h;
        w1tl[(size_t)c * DIM + k] = l;
    }
}

// W2 [128][512] -> transposed split w2th/w2tl [512 col][128 k] bf16
__global__ void k_w2prep(const float* __restrict__ W2, ushort* __restrict__ w2th, ushort* __restrict__ w2tl) {
    int c = blockIdx.x;
    int t = threadIdx.x;   // 128
    float v = W2[(size_t)t * FD + c];
    ushort h, l;
    split2t(v, h, l);
    w2th[(size_t)c * HID + t] = h;
    w2tl[(size_t)c * HID + t] = l;
}

// kA: h = relu(X @ W1 + b1) via split-bf16 MFMA (3 products). 128 rows x 128 cols per block.
// X converted f32->bf16h/l in regs, ds_written with XOR swizzle; W1T staged via global_load_lds.
__global__ __launch_bounds__(256) void kA(const float* __restrict__ X, const ushort* __restrict__ w1th,
                                          const ushort* __restrict__ w1tl, const float* __restrict__ b1,
                                          ushort* __restrict__ hh, ushort* __restrict__ hl) {
    __shared__ __align__(16) char lds[65536];   // xh | xl | wh | wl (16 KB each)
    int t = threadIdx.x;
    int lane = t & 63, w = t >> 6;
    int wr = w >> 1, wc = w & 1;
    int n0 = blockIdx.x * 128;
    f32x4 zero4 = {0.f, 0.f, 0.f, 0.f};
    f32x4 acc[4][4];
    #pragma unroll
    for (int i = 0; i < 4; ++i)
        #pragma unroll
        for (int j = 0; j < 4; ++j) acc[i][j] = zero4;

    int xr = t >> 1;                 // row this thread converts
    int cb0 = (t & 1) * 4;           // chunk base (each chunk = 8 bf16 = 16 B)
    int xsw = xr & 7;

    for (int k0 = 0; k0 < DIM; k0 += 64) {
        #pragma unroll
        for (int i = 0; i < 4; ++i) {
            int rr = w * 32 + i * 8;
            int row = rr + (lane >> 3);
            int csrc = (lane & 7) ^ (row & 7);
            size_t goff = (size_t)row * DIM + k0 + csrc * 8;
            async_cp16(w1th + goff, lds + 32768 + rr * 128);
            async_cp16(w1tl + goff, lds + 49152 + rr * 128);
        }
        const float* xp = X + (size_t)(n0 + xr) * DIM + k0 + cb0 * 8;
        #pragma unroll
        for (int c = 0; c < 4; ++c) {
            float4 a = *(const float4*)(xp + c * 8);
            float4 b = *(const float4*)(xp + c * 8 + 4);
            float v[8] = {a.x, a.y, a.z, a.w, b.x, b.y, b.z, b.w};
            uint32_t hu[4], lu[4];
            #pragma unroll
            for (int e = 0; e < 4; ++e) {
                ushort h0, l0, h1, l1;
                split2t(v[2 * e], h0, l0);
                split2t(v[2 * e + 1], h1, l1);
                hu[e] = (uint32_t)h0 | ((uint32_t)h1 << 16);
                lu[e] = (uint32_t)l0 | ((uint32_t)l1 << 16);
            }
            int slot = (size_t)xr * 128 + (((cb0 + c) ^ xsw) << 4);
            *(uint4*)(lds + slot) = make_uint4(hu[0], hu[1], hu[2], hu[3]);
            *(uint4*)(lds + 16384 + slot) = make_uint4(lu[0], lu[1], lu[2], lu[3]);
        }
        __syncthreads();
        #pragma unroll
        for (int kh = 0; kh < 2; ++kh) {
            int ch = kh * 4 + (lane >> 4);
            sh8 ah[4], al[4], bh[4], bl[4];
            #pragma unroll
            for (int i = 0; i < 4; ++i) {
                int ra = wr * 64 + i * 16 + (lane & 15);
                int off = ra * 128 + ((ch ^ (ra & 7)) << 4);
                ah[i] = *(const sh8*)(lds + off);
                al[i] = *(const sh8*)(lds + 16384 + off);
            }
            #pragma unroll
            for (int j = 0; j < 4; ++j) {
                int rb = wc * 64 + j * 16 + (lane & 15);
                int off = rb * 128 + ((ch ^ (rb & 7)) << 4);
                bh[j] = *(const sh8*)(lds + 32768 + off);
                bl[j] = *(const sh8*)(lds + 49152 + off);
            }
            #pragma unroll
            for (int i = 0; i < 4; ++i)
                #pragma unroll
                for (int j = 0; j < 4; ++j) {
                    acc[i][j] = __builtin_amdgcn_mfma_f32_16x16x32_bf16(ah[i], bh[j], acc[i][j], 0, 0, 0);
                    acc[i][j] = __builtin_amdgcn_mfma_f32_16x16x32_bf16(ah[i], bl[j], acc[i][j], 0, 0, 0);
                    acc[i][j] = __builtin_amdgcn_mfma_f32_16x16x32_bf16(al[i], bh[j], acc[i][j], 0, 0, 0);
                }
        }
        __syncthreads();
    }
    int lane15 = lane & 15, lg = lane >> 4;
    #pragma unroll
    for (int j = 0; j < 4; ++j) {
        int gcol = wc * 64 + j * 16 + lane15;
        float b1v = b1[gcol];
        #pragma unroll
        for (int i = 0; i < 4; ++i)
            #pragma unroll
            for (int r = 0; r < 4; ++r) {
                int grow = n0 + wr * 64 + i * 16 + lg * 4 + r;
                float v = fmaxf(acc[i][j][r] + b1v, 0.f);
                ushort hv, lv;
                split2t(v, hv, lv);
                hh[(size_t)grow * HID + gcol] = hv;
                hl[(size_t)grow * HID + gcol] = lv;
            }
    }
}

// kB: z = h @ W2 + b2 via split-bf16 MFMA. 32 rows/block, K=128 single stage; B-frags from L2.
// Epilogue: zbh/zbl split + f32 row norms zz.
__global__ __launch_bounds__(256) void kB(const ushort* __restrict__ hh, const ushort* __restrict__ hl,
                                          const ushort* __restrict__ w2th, const ushort* __restrict__ w2tl,
                                          const float* __restrict__ b2,
                                          ushort* __restrict__ zbh, ushort* __restrict__ zbl,
                                          float* __restrict__ zz) {
    __shared__ __align__(16) char lds[16384];   // ah-tile 8K | al-tile 8K  (32 rows x 256 B)
    __shared__ float zzp[4][32];
    int t = threadIdx.x;
    int lane = t & 63, w = t >> 6;
    int n0 = blockIdx.x * 32;
    #pragma unroll
    for (int i = 0; i < 2; ++i) {
        int rr = w * 8 + i * 4;
        int row = rr + (lane >> 4);
        int csrc = (lane & 15) ^ (row & 7);
        size_t goff = (size_t)(n0 + row) * HID + csrc * 8;
        async_cp16(hh + goff, lds + rr * 256);
        async_cp16(hl + goff, lds + 8192 + rr * 256);
    }
    f32x4 zero4 = {0.f, 0.f, 0.f, 0.f};
    f32x4 acc[2][8];
    #pragma unroll
    for (int i = 0; i < 2; ++i)
        #pragma unroll
        for (int j = 0; j < 8; ++j) acc[i][j] = zero4;
    __syncthreads();
    #pragma unroll
    for (int kh = 0; kh < 4; ++kh) {
        int ch = kh * 4 + (lane >> 4);
        sh8 ah[2], al[2];
        #pragma unroll
        for (int i = 0; i < 2; ++i) {
            int ra = i * 16 + (lane & 15);
            int off = ra * 256 + ((ch ^ (ra & 7)) << 4);
            ah[i] = *(const sh8*)(lds + off);
            al[i] = *(const sh8*)(lds + 8192 + off);
        }
        #pragma unroll
        for (int j = 0; j < 8; ++j) {
            int col = w * 128 + j * 16 + (lane & 15);
            size_t gof = (size_t)col * HID + ch * 8;
            sh8 bh = *(const sh8*)(w2th + gof);
            sh8 bl = *(const sh8*)(w2tl + gof);
            #pragma unroll
            for (int i = 0; i < 2; ++i) {
                acc[i][j] = __builtin_amdgcn_mfma_f32_16x16x32_bf16(ah[i], bh, acc[i][j], 0, 0, 0);
                acc[i][j] = __builtin_amdgcn_mfma_f32_16x16x32_bf16(ah[i], bl, acc[i][j], 0, 0, 0);
                acc[i][j] = __builtin_amdgcn_mfma_f32_16x16x32_bf16(al[i], bh, acc[i][j], 0, 0, 0);
            }
        }
    }
    int lane15 = lane & 15, lg = lane >> 4;
    float b2v[8];
    #pragma unroll
    for (int j = 0; j < 8; ++j) b2v[j] = b2[w * 128 + j * 16 + lane15];
    #pragma unroll
    for (int i = 0; i < 2; ++i)
        #pragma unroll
        for (int r = 0; r < 4; ++r) {
            int lrow = i * 16 + lg * 4 + r;
            size_t rowb = (size_t)(n0 + lrow) * FD;
            float s = 0.f;
            #pragma unroll
            for (int j = 0; j < 8; ++j) {
                float v = acc[i][j][r] + b2v[j];
                int col = w * 128 + j * 16 + lane15;
                ushort hv, lv;
                split2t(v, hv, lv);
                zbh[rowb + col] = hv;
                zbl[rowb + col] = lv;
                s = fmaf(v, v, s);
            }
            s += __shfl_xor(s, 1, 64); s += __shfl_xor(s, 2, 64);
            s += __shfl_xor(s, 4, 64); s += __shfl_xor(s, 8, 64);
            if (lane15 == 0) zzp[w][lrow] = s;
        }
    __syncthreads();
    if (t < 32) zz[n0 + t] = zzp[0][t] + zzp[1][t] + zzp[2][t] + zzp[3][t];
}

// Distance GEMM via split-bf16 MFMA (unchanged from round 3)
__global__ __launch_bounds__(256) void k_mfma3(const ushort* __restrict__ zbh, const ushort* __restrict__ zbl,
                                               const ushort* __restrict__ cbh, const ushort* __restrict__ cbl,
                                               const float* __restrict__ zz, const double* __restrict__ cc,
                                               float* __restrict__ nd) {
    __shared__ __align__(16) char lds[65536];
    int t = threadIdx.x;
    int lane = t & 63, w = t >> 6;
    int wr = w >> 1, wc = w & 1;
    int bid = blockIdx.x;
    int bm = ((bid >> 6) << 3) | (bid & 7);
    int bkn = (bid >> 3) & 7;
    const ushort* Ahg = zbh + (size_t)bm * 128 * FD;
    const ushort* Alg = zbl + (size_t)bm * 128 * FD;
    const ushort* Bhg = cbh + (size_t)bkn * 128 * FD;
    const ushort* Blg = cbl + (size_t)bkn * 128 * FD;

    f32x4 zero4 = {0.f, 0.f, 0.f, 0.f};
    f32x4 acc[4][4];
    #pragma unroll
    for (int i = 0; i < 4; ++i)
        #pragma unroll
        for (int j = 0; j < 4; ++j) acc[i][j] = zero4;

    for (int k0 = 0; k0 < FD; k0 += 64) {
        #pragma unroll
        for (int i = 0; i < 4; ++i) {
            int rr = w * 32 + i * 8;
            int row = rr + (lane >> 3);
            int csrc = (lane & 7) ^ (row & 7);
            size_t goff = (size_t)row * FD + k0 + csrc * 8;
            async_cp16(Ahg + goff, lds + rr * 128);
            async_cp16(Alg + goff, lds + 16384 + rr * 128);
            async_cp16(Bhg + goff, lds + 32768 + rr * 128);
            async_cp16(Blg + goff, lds + 49152 + rr * 128);
        }
        __syncthreads();
        #pragma unroll
        for (int kh = 0; kh < 2; ++kh) {
            int ch = kh * 4 + (lane >> 4);
            sh8 ah[4], al[4], bh[4], bl[4];
            #pragma unroll
            for (int i = 0; i < 4; ++i) {
                int ra = wr * 64 + i * 16 + (lane & 15);
                int off = ra * 128 + ((ch ^ (ra & 7)) << 4);
                ah[i] = *(const sh8*)(lds + off);
                al[i] = *(const sh8*)(lds + 16384 + off);
            }
            #pragma unroll
            for (int j = 0; j < 4; ++j) {
                int rb = wc * 64 + j * 16 + (lane & 15);
                int off = rb * 128 + ((ch ^ (rb & 7)) << 4);
                bh[j] = *(const sh8*)(lds + 32768 + off);
                bl[j] = *(const sh8*)(lds + 49152 + off);
            }
            #pragma unroll
            for (int i = 0; i < 4; ++i)
                #pragma unroll
                for (int j = 0; j < 4; ++j) {
                    acc[i][j] = __builtin_amdgcn_mfma_f32_16x16x32_bf16(ah[i], bh[j], acc[i][j], 0, 0, 0);
                    acc[i][j] = __builtin_amdgcn_mfma_f32_16x16x32_bf16(ah[i], bl[j], acc[i][j], 0, 0, 0);
                    acc[i][j] = __builtin_amdgcn_mfma_f32_16x16x32_bf16(al[i], bh[j], acc[i][j], 0, 0, 0);
                }
        }
        __syncthreads();
    }
    int lane15 = lane & 15, lg = lane >> 4;
    int gcol[4];
    double ccv[4];
    #pragma unroll
    for (int j = 0; j < 4; ++j) {
        gcol[j] = bkn * 128 + wc * 64 + j * 16 + lane15;
        ccv[j] = cc[gcol[j]];
    }
    #pragma unroll
    for (int i = 0; i < 4; ++i)
        #pragma unroll
        for (int r = 0; r < 4; ++r) {
            int grow = bm * 128 + wr * 64 + i * 16 + lg * 4 + r;
            double zv = (double)zz[grow];
            size_t rowoff = (size_t)grow << 10;
            #pragma unroll
            for (int j = 0; j < 4; ++j)
                nd[rowoff + gcol[j]] = (float)(2.0 * (double)acc[i][j][r] - zv - ccv[j]);
        }
}

__global__ __launch_bounds__(256) void k_sample(const float* __restrict__ nd, const float* __restrict__ zz,
                                                int* __restrict__ idx, int* __restrict__ counts) {
    int n = blockIdx.x;
    int t = threadIdx.x;
    float zzn0 = zz[n], zzn1 = zz[n + 32768];
    float best0 = -1e30f, best1 = -1e30f;
    int bi0 = 0, bi1 = 0;
    for (int k = t; k < KCB; k += 256) {
        uint32_t ctr = (uint32_t)(n * KCB + k);
        uint32_t r0, r1;
        threefry(ctr, ctr + HALFCNT, r0, r1);
        float g0 = gumbel_f32(r0), g1 = gumbel_f32(r1);
        float s0 = (nd[(size_t)n * KCB + k] + zzn0) * 10.0f + g0;
        float s1 = (nd[(size_t)(n + 32768) * KCB + k] + zzn1) * 10.0f + g1;
        if (s0 > best0) { best0 = s0; bi0 = k; }
        if (s1 > best1) { best1 = s1; bi1 = k; }
    }
    __shared__ float sv0[256], sv1[256];
    __shared__ int si0[256], si1[256];
    sv0[t] = best0; si0[t] = bi0; sv1[t] = best1; si1[t] = bi1;
    __syncthreads();
    for (int off = 128; off; off >>= 1) {
        if (t < off) {
            if (sv0[t + off] > sv0[t] || (sv0[t + off] == sv0[t] && si0[t + off] < si0[t])) {
                sv0[t] = sv0[t + off]; si0[t] = si0[t + off];
            }
            if (sv1[t + off] > sv1[t] || (sv1[t + off] == sv1[t] && si1[t + off] < si1[t])) {
                sv1[t] = sv1[t + off]; si1[t] = si1[t + off];
            }
        }
        __syncthreads();
    }
    if (t == 0) {
        idx[n] = si0[0];
        idx[n + 32768] = si1[0];
        atomicAdd(&counts[si0[0]], 1);
        atomicAdd(&counts[si1[0]], 1);
    }
}

// qz = cb[idx[n]] (exact: ref's z+(q-z) == q in f64); loss from (c - (zh+zl))^2, binned atomics.
__global__ __launch_bounds__(256) void k_qloss(const ushort* __restrict__ zbh, const ushort* __restrict__ zbl,
                                               const float* __restrict__ cb, const int* __restrict__ idx,
                                               float* __restrict__ qz, double* __restrict__ lossb) {
    size_t tid = (size_t)blockIdx.x * 256 + threadIdx.x;
    size_t base = tid * 8;
    int n = (int)(base >> 9);
    int f = (int)(base & 511);
    int ki = idx[n];
    uint4 hv = *(const uint4*)(zbh + base);
    uint4 lv = *(const uint4*)(zbl + base);
    float4 c0 = *(const float4*)(cb + (size_t)ki * FD + f);
    float4 c1 = *(const float4*)(cb + (size_t)ki * FD + f + 4);
    uint32_t hs[4] = {hv.x, hv.y, hv.z, hv.w};
    uint32_t ls[4] = {lv.x, lv.y, lv.z, lv.w};
    float cv[8] = {c0.x, c0.y, c0.z, c0.w, c1.x, c1.y, c1.z, c1.w};
    double local = 0.0;
    #pragma unroll
    for (int e = 0; e < 4; ++e) {
        float z0 = __uint_as_float(hs[e] << 16) + __uint_as_float(ls[e] << 16);
        float z1 = __uint_as_float(hs[e] & 0xFFFF0000u) + __uint_as_float(ls[e] & 0xFFFF0000u);
        double d0 = (double)cv[2 * e] - (double)z0;
        double d1 = (double)cv[2 * e + 1] - (double)z1;
        local = fma(d0, d0, local);
        local = fma(d1, d1, local);
    }
    *(float4*)(qz + base) = c0;
    *(float4*)(qz + base + 4) = c1;
    for (int off = 32; off; off >>= 1) local += __shfl_down(local, off, 64);
    __shared__ double red[4];
    int lane = threadIdx.x & 63, w = threadIdx.x >> 6;
    if (lane == 0) red[w] = local;
    __syncthreads();
    if (threadIdx.x == 0) atomicAdd(&lossb[blockIdx.x & 255], red[0] + red[1] + red[2] + red[3]);
}

__global__ void k_zero_enc(float* __restrict__ enc) {
    size_t i = (size_t)blockIdx.x * blockDim.x + threadIdx.x;
    size_t stride = (size_t)gridDim.x * blockDim.x;
    float4* p = (float4*)enc;
    size_t n4 = (size_t)N_ROWS * KCB / 4;
    float4 zv = make_float4(0.f, 0.f, 0.f, 0.f);
    for (size_t j = i; j < n4; j += stride) p[j] = zv;
}

__global__ void k_scatter(float* __restrict__ enc, const int* __restrict__ idx) {
    int n = blockIdx.x * 256 + threadIdx.x;
    enc[(size_t)n * KCB + idx[n]] = 1.0f;
}

__global__ void k_scalars(const int* __restrict__ counts, const double* __restrict__ lossb,
                          float* __restrict__ out) {
    int t = threadIdx.x;
    double s = 0.0;
    for (int k = t; k < KCB; k += 256) {
        double p = (double)counts[k] * (1.0 / 65536.0);
        s += p * log(p + 1e-10);
    }
    double lsum = lossb[t];
    for (int off = 32; off; off >>= 1) {
        s += __shfl_down(s, off, 64);
        lsum += __shfl_down(lsum, off, 64);
    }
    __shared__ double red[4], redl[4];
    int lane = t & 63, w = t >> 6;
    if (lane == 0) { red[w] = s; redl[w] = lsum; }
    __syncthreads();
    if (t == 0) {
        double tot = red[0] + red[1] + red[2] + red[3];
        double ltot = redl[0] + redl[1] + redl[2] + redl[3];
        out[OFF_PERP] = (float)exp(-tot);
        out[0] = (float)(ltot * (2.0 / 33554432.0));
    }
}

extern "C" void kernel_launch(void* const* d_in, const int* in_sizes, int n_in,
                              void* d_out, int out_size, void* d_ws, size_t ws_size,
                              hipStream_t stream) {
    const float* X  = (const float*)d_in[0];
    const float* W1 = (const float*)d_in[1];
    const float* b1 = (const float*)d_in[2];
    const float* W2 = (const float*)d_in[3];
    const float* b2 = (const float*)d_in[4];
    const float* cb = (const float*)d_in[5];

    float* out = (float*)d_out;
    float* qz  = out + (size_t)OFF_Q;
    float* enc = out + (size_t)OFF_ENC;
    float* nd  = out + (size_t)OFF_ND;

    // scratch buffers inside the enc region (zeroed at the end, before scatter)
    ushort* ub   = (ushort*)(enc + 2);           // 16B-aligned base
    ushort* zbh  = ub;                           // [65536*512]
    ushort* zbl  = ub + 33554432;
    ushort* cbh  = ub + 67108864;                // [1024*512]
    ushort* cbl  = ub + 67633152;
    ushort* hh   = ub + 68157440;                // [65536*128]
    ushort* hl   = ub + 76546048;
    ushort* w1th = ub + 84934656;                // [128*1024]
    ushort* w1tl = ub + 85065728;
    ushort* w2th = ub + 85196800;                // [512*128]
    ushort* w2tl = ub + 85262336;

    float* zz = (float*)d_ws;            // [65536]
    double* cc = (double*)(zz + 65536);  // [1024]
    double* lossb = cc + 1024;           // [256]
    int* counts = (int*)(lossb + 256);   // [1024]
    int* idx = counts + 1024;            // [65536]

    k_init<<<1, 256, 0, stream>>>(counts, lossb);
    k_cbprep<<<1024, 64, 0, stream>>>(cb, cbh, cbl, cc);
    k_w1prep<<<128, 256, 0, stream>>>(W1, w1th, w1tl);
    k_w2prep<<<512, 128, 0, stream>>>(W2, w2th, w2tl);
    kA<<<512, 256, 0, stream>>>(X, w1th, w1tl, b1, hh, hl);
    kB<<<2048, 256, 0, stream>>>(hh, hl, w2th, w2tl, b2, zbh, zbl, zz);
    k_mfma3<<<4096, 256, 0, stream>>>(zbh, zbl, cbh, cbl, zz, cc, nd);
    k_sample<<<32768, 256, 0, stream>>>(nd, zz, idx, counts);
    k_qloss<<<16384, 256, 0, stream>>>(zbh, zbl, cb, idx, qz, lossb);
    k_zero_enc<<<8192, 256, 0, stream>>>(enc);
    k_scatter<<<256, 256, 0, stream>>>(enc, idx);
    k_scalars<<<1, 256, 0, stream>>>(counts, lossb, out);
}

// Round 5
// 631.085 us; speedup vs baseline: 5.9684x; 1.1694x over previous
//
#include <hip/hip_runtime.h>
#include <stdint.h>

#define N_ROWS 65536
#define DIM 1024
#define HID 128
#define FD 512
#define KCB 1024
#define HALFCNT 33554432u

#define OFF_Q    1
#define OFF_PERP 33554433
#define OFF_ENC  33554434
#define OFF_ND   100663298

typedef __attribute__((ext_vector_type(8))) short sh8;     // 8 bf16 in 4 VGPRs
typedef __attribute__((ext_vector_type(4))) float f32x4;

__device__ __forceinline__ uint32_t rotl32(uint32_t v, int r) { return (v << r) | (v >> (32 - r)); }

// JAX threefry2x32 with key (0, 42)
__device__ __forceinline__ void threefry(uint32_t c0, uint32_t c1, uint32_t& o0, uint32_t& o1) {
    const uint32_t ks0 = 0u, ks1 = 42u, ks2 = 0x1BD11BDAu ^ 0u ^ 42u;
    uint32_t x0 = c0 + ks0, x1 = c1 + ks1;
#define TFR(r) x0 += x1; x1 = rotl32(x1, r); x1 ^= x0;
    TFR(13) TFR(15) TFR(26) TFR(6)  x0 += ks1; x1 += ks2 + 1u;
    TFR(17) TFR(29) TFR(16) TFR(24) x0 += ks2; x1 += ks0 + 2u;
    TFR(13) TFR(15) TFR(26) TFR(6)  x0 += ks0; x1 += ks1 + 3u;
    TFR(17) TFR(29) TFR(16) TFR(24) x0 += ks1; x1 += ks2 + 4u;
    TFR(13) TFR(15) TFR(26) TFR(6)  x0 += ks2; x1 += ks0 + 5u;
#undef TFR
    o0 = x0; o1 = x1;
}

__device__ __forceinline__ float gumbel_f32(uint32_t b) {
    uint32_t m = b >> 9;
    float u = m ? (float)m * 1.1920928955078125e-07f : 1.17549435e-38f;
    return -logf(-logf(u));
}

__device__ __forceinline__ ushort bf16rne(float f) {
    uint32_t u = __float_as_uint(f);
    return (ushort)((u + 0x7FFFu + ((u >> 16) & 1u)) >> 16);
}
// trunc-hi split: h = bit-truncate, l = RNE(v - h).
__device__ __forceinline__ void split2t(float v, ushort& h, ushort& l) {
    uint32_t u = __float_as_uint(v);
    h = (ushort)(u >> 16);
    float hf = __uint_as_float(u & 0xFFFF0000u);
    l = bf16rne(v - hf);
}

// async global->LDS, 16B per lane; LDS dest = wave-uniform base + lane*16
__device__ __forceinline__ void async_cp16(const void* g, void* l) {
    __builtin_amdgcn_global_load_lds(
        (const __attribute__((address_space(1))) void*)g,
        (__attribute__((address_space(3))) void*)l, 16, 0, 0);
}

// Fused prep: [0,256) codebook split+norms (4 rows/block); [256,384) W1T split;
// [384,640) W2T split (2 cols/block); [640] zero counts/lossb.
__global__ __launch_bounds__(256) void k_prep(const float* __restrict__ cb, const float* __restrict__ W1,
                                              const float* __restrict__ W2,
                                              ushort* __restrict__ cbh, ushort* __restrict__ cbl,
                                              double* __restrict__ cc,
                                              ushort* __restrict__ w1th, ushort* __restrict__ w1tl,
                                              ushort* __restrict__ w2th, ushort* __restrict__ w2tl,
                                              int* __restrict__ counts, double* __restrict__ lossb) {
    int gb = blockIdx.x, t = threadIdx.x;
    if (gb < 256) {
        int k = gb * 4 + (t >> 6), l = t & 63;
        const float4* row = (const float4*)(cb + (size_t)k * FD);
        float4 a = row[l * 2], b = row[l * 2 + 1];
        float v[8] = {a.x, a.y, a.z, a.w, b.x, b.y, b.z, b.w};
        uint32_t hu[4], lu[4];
        double s = 0.0;
        #pragma unroll
        for (int e = 0; e < 4; ++e) {
            ushort h0, l0, h1, l1;
            split2t(v[2 * e], h0, l0);
            split2t(v[2 * e + 1], h1, l1);
            hu[e] = (uint32_t)h0 | ((uint32_t)h1 << 16);
            lu[e] = (uint32_t)l0 | ((uint32_t)l1 << 16);
            s = fma((double)v[2 * e], (double)v[2 * e], s);
            s = fma((double)v[2 * e + 1], (double)v[2 * e + 1], s);
        }
        *(uint4*)(cbh + (size_t)k * FD + l * 8) = make_uint4(hu[0], hu[1], hu[2], hu[3]);
        *(uint4*)(cbl + (size_t)k * FD + l * 8) = make_uint4(lu[0], lu[1], lu[2], lu[3]);
        for (int off = 32; off; off >>= 1) s += __shfl_down(s, off, 64);
        if (l == 0) cc[k] = s;
    } else if (gb < 384) {
        int c = gb - 256;
        #pragma unroll
        for (int u = 0; u < 4; ++u) {
            int k = t + u * 256;
            float v = W1[(size_t)k * HID + c];
            ushort h, l;
            split2t(v, h, l);
            w1th[(size_t)c * DIM + k] = h;
            w1tl[(size_t)c * DIM + k] = l;
        }
    } else if (gb < 640) {
        int c = (gb - 384) * 2 + (t >> 7);
        int tt = t & 127;
        float v = W2[(size_t)tt * FD + c];
        ushort h, l;
        split2t(v, h, l);
        w2th[(size_t)c * HID + tt] = h;
        w2tl[(size_t)c * HID + tt] = l;
    } else {
        for (int k = t; k < KCB; k += 256) counts[k] = 0;
        lossb[t] = 0.0;
    }
}

// kA: h = relu(X @ W1 + b1) via split-bf16 MFMA (3 products). 128x128/block.
__global__ __launch_bounds__(256) void kA(const float* __restrict__ X, const ushort* __restrict__ w1th,
                                          const ushort* __restrict__ w1tl, const float* __restrict__ b1,
                                          ushort* __restrict__ hh, ushort* __restrict__ hl) {
    __shared__ __align__(16) char lds[65536];   // xh | xl | wh | wl (16 KB each)
    int t = threadIdx.x;
    int lane = t & 63, w = t >> 6;
    int wr = w >> 1, wc = w & 1;
    int n0 = blockIdx.x * 128;
    f32x4 zero4 = {0.f, 0.f, 0.f, 0.f};
    f32x4 acc[4][4];
    #pragma unroll
    for (int i = 0; i < 4; ++i)
        #pragma unroll
        for (int j = 0; j < 4; ++j) acc[i][j] = zero4;

    int xr = t >> 1;
    int cb0 = (t & 1) * 4;
    int xsw = xr & 7;

    for (int k0 = 0; k0 < DIM; k0 += 64) {
        #pragma unroll
        for (int i = 0; i < 4; ++i) {
            int rr = w * 32 + i * 8;
            int row = rr + (lane >> 3);
            int csrc = (lane & 7) ^ (row & 7);
            size_t goff = (size_t)row * DIM + k0 + csrc * 8;
            async_cp16(w1th + goff, lds + 32768 + rr * 128);
            async_cp16(w1tl + goff, lds + 49152 + rr * 128);
        }
        const float* xp = X + (size_t)(n0 + xr) * DIM + k0 + cb0 * 8;
        #pragma unroll
        for (int c = 0; c < 4; ++c) {
            float4 a = *(const float4*)(xp + c * 8);
            float4 b = *(const float4*)(xp + c * 8 + 4);
            float v[8] = {a.x, a.y, a.z, a.w, b.x, b.y, b.z, b.w};
            uint32_t hu[4], lu[4];
            #pragma unroll
            for (int e = 0; e < 4; ++e) {
                ushort h0, l0, h1, l1;
                split2t(v[2 * e], h0, l0);
                split2t(v[2 * e + 1], h1, l1);
                hu[e] = (uint32_t)h0 | ((uint32_t)h1 << 16);
                lu[e] = (uint32_t)l0 | ((uint32_t)l1 << 16);
            }
            int slot = (size_t)xr * 128 + (((cb0 + c) ^ xsw) << 4);
            *(uint4*)(lds + slot) = make_uint4(hu[0], hu[1], hu[2], hu[3]);
            *(uint4*)(lds + 16384 + slot) = make_uint4(lu[0], lu[1], lu[2], lu[3]);
        }
        __syncthreads();
        #pragma unroll
        for (int kh = 0; kh < 2; ++kh) {
            int ch = kh * 4 + (lane >> 4);
            sh8 ah[4], al[4], bh[4], bl[4];
            #pragma unroll
            for (int i = 0; i < 4; ++i) {
                int ra = wr * 64 + i * 16 + (lane & 15);
                int off = ra * 128 + ((ch ^ (ra & 7)) << 4);
                ah[i] = *(const sh8*)(lds + off);
                al[i] = *(const sh8*)(lds + 16384 + off);
            }
            #pragma unroll
            for (int j = 0; j < 4; ++j) {
                int rb = wc * 64 + j * 16 + (lane & 15);
                int off = rb * 128 + ((ch ^ (rb & 7)) << 4);
                bh[j] = *(const sh8*)(lds + 32768 + off);
                bl[j] = *(const sh8*)(lds + 49152 + off);
            }
            #pragma unroll
            for (int i = 0; i < 4; ++i)
                #pragma unroll
                for (int j = 0; j < 4; ++j) {
                    acc[i][j] = __builtin_amdgcn_mfma_f32_16x16x32_bf16(ah[i], bh[j], acc[i][j], 0, 0, 0);
                    acc[i][j] = __builtin_amdgcn_mfma_f32_16x16x32_bf16(ah[i], bl[j], acc[i][j], 0, 0, 0);
                    acc[i][j] = __builtin_amdgcn_mfma_f32_16x16x32_bf16(al[i], bh[j], acc[i][j], 0, 0, 0);
                }
        }
        __syncthreads();
    }
    int lane15 = lane & 15, lg = lane >> 4;
    #pragma unroll
    for (int j = 0; j < 4; ++j) {
        int gcol = wc * 64 + j * 16 + lane15;
        float b1v = b1[gcol];
        #pragma unroll
        for (int i = 0; i < 4; ++i)
            #pragma unroll
            for (int r = 0; r < 4; ++r) {
                int grow = n0 + wr * 64 + i * 16 + lg * 4 + r;
                float v = fmaxf(acc[i][j][r] + b1v, 0.f);
                ushort hv, lv;
                split2t(v, hv, lv);
                hh[(size_t)grow * HID + gcol] = hv;
                hl[(size_t)grow * HID + gcol] = lv;
            }
    }
}

// kB: z = h @ W2 + b2 via split-bf16 MFMA. 32 rows/block, K=128; epilogue: z splits + zz.
__global__ __launch_bounds__(256) void kB(const ushort* __restrict__ hh, const ushort* __restrict__ hl,
                                          const ushort* __restrict__ w2th, const ushort* __restrict__ w2tl,
                                          const float* __restrict__ b2,
                                          ushort* __restrict__ zbh, ushort* __restrict__ zbl,
                                          float* __restrict__ zz) {
    __shared__ __align__(16) char lds[16384];
    __shared__ float zzp[4][32];
    int t = threadIdx.x;
    int lane = t & 63, w = t >> 6;
    int n0 = blockIdx.x * 32;
    #pragma unroll
    for (int i = 0; i < 2; ++i) {
        int rr = w * 8 + i * 4;
        int row = rr + (lane >> 4);
        int csrc = (lane & 15) ^ (row & 7);
        size_t goff = (size_t)(n0 + row) * HID + csrc * 8;
        async_cp16(hh + goff, lds + rr * 256);
        async_cp16(hl + goff, lds + 8192 + rr * 256);
    }
    f32x4 zero4 = {0.f, 0.f, 0.f, 0.f};
    f32x4 acc[2][8];
    #pragma unroll
    for (int i = 0; i < 2; ++i)
        #pragma unroll
        for (int j = 0; j < 8; ++j) acc[i][j] = zero4;
    __syncthreads();
    #pragma unroll
    for (int kh = 0; kh < 4; ++kh) {
        int ch = kh * 4 + (lane >> 4);
        sh8 ah[2], al[2];
        #pragma unroll
        for (int i = 0; i < 2; ++i) {
            int ra = i * 16 + (lane & 15);
            int off = ra * 256 + ((ch ^ (ra & 7)) << 4);
            ah[i] = *(const sh8*)(lds + off);
            al[i] = *(const sh8*)(lds + 8192 + off);
        }
        #pragma unroll
        for (int j = 0; j < 8; ++j) {
            int col = w * 128 + j * 16 + (lane & 15);
            size_t gof = (size_t)col * HID + ch * 8;
            sh8 bh = *(const sh8*)(w2th + gof);
            sh8 bl = *(const sh8*)(w2tl + gof);
            #pragma unroll
            for (int i = 0; i < 2; ++i) {
                acc[i][j] = __builtin_amdgcn_mfma_f32_16x16x32_bf16(ah[i], bh, acc[i][j], 0, 0, 0);
                acc[i][j] = __builtin_amdgcn_mfma_f32_16x16x32_bf16(ah[i], bl, acc[i][j], 0, 0, 0);
                acc[i][j] = __builtin_amdgcn_mfma_f32_16x16x32_bf16(al[i], bh, acc[i][j], 0, 0, 0);
            }
        }
    }
    int lane15 = lane & 15, lg = lane >> 4;
    float b2v[8];
    #pragma unroll
    for (int j = 0; j < 8; ++j) b2v[j] = b2[w * 128 + j * 16 + lane15];
    #pragma unroll
    for (int i = 0; i < 2; ++i)
        #pragma unroll
        for (int r = 0; r < 4; ++r) {
            int lrow = i * 16 + lg * 4 + r;
            size_t rowb = (size_t)(n0 + lrow) * FD;
            float s = 0.f;
            #pragma unroll
            for (int j = 0; j < 8; ++j) {
                float v = acc[i][j][r] + b2v[j];
                int col = w * 128 + j * 16 + lane15;
                ushort hv, lv;
                split2t(v, hv, lv);
                zbh[rowb + col] = hv;
                zbl[rowb + col] = lv;
                s = fmaf(v, v, s);
            }
            s += __shfl_xor(s, 1, 64); s += __shfl_xor(s, 2, 64);
            s += __shfl_xor(s, 4, 64); s += __shfl_xor(s, 8, 64);
            if (lane15 == 0) zzp[w][lrow] = s;
        }
    __syncthreads();
    if (t < 32) zz[n0 + t] = zzp[0][t] + zzp[1][t] + zzp[2][t] + zzp[3][t];
}

// Distance GEMM via split-bf16 MFMA (numerics identical to round 3/4).
__global__ __launch_bounds__(256) void k_mfma3(const ushort* __restrict__ zbh, const ushort* __restrict__ zbl,
                                               const ushort* __restrict__ cbh, const ushort* __restrict__ cbl,
                                               const float* __restrict__ zz, const double* __restrict__ cc,
                                               float* __restrict__ nd) {
    __shared__ __align__(16) char lds[65536];
    int t = threadIdx.x;
    int lane = t & 63, w = t >> 6;
    int wr = w >> 1, wc = w & 1;
    int bid = blockIdx.x;
    int bm = ((bid >> 6) << 3) | (bid & 7);
    int bkn = (bid >> 3) & 7;
    const ushort* Ahg = zbh + (size_t)bm * 128 * FD;
    const ushort* Alg = zbl + (size_t)bm * 128 * FD;
    const ushort* Bhg = cbh + (size_t)bkn * 128 * FD;
    const ushort* Blg = cbl + (size_t)bkn * 128 * FD;

    f32x4 zero4 = {0.f, 0.f, 0.f, 0.f};
    f32x4 acc[4][4];
    #pragma unroll
    for (int i = 0; i < 4; ++i)
        #pragma unroll
        for (int j = 0; j < 4; ++j) acc[i][j] = zero4;

    for (int k0 = 0; k0 < FD; k0 += 64) {
        #pragma unroll
        for (int i = 0; i < 4; ++i) {
            int rr = w * 32 + i * 8;
            int row = rr + (lane >> 3);
            int csrc = (lane & 7) ^ (row & 7);
            size_t goff = (size_t)row * FD + k0 + csrc * 8;
            async_cp16(Ahg + goff, lds + rr * 128);
            async_cp16(Alg + goff, lds + 16384 + rr * 128);
            async_cp16(Bhg + goff, lds + 32768 + rr * 128);
            async_cp16(Blg + goff, lds + 49152 + rr * 128);
        }
        __syncthreads();
        #pragma unroll
        for (int kh = 0; kh < 2; ++kh) {
            int ch = kh * 4 + (lane >> 4);
            sh8 ah[4], al[4], bh[4], bl[4];
            #pragma unroll
            for (int i = 0; i < 4; ++i) {
                int ra = wr * 64 + i * 16 + (lane & 15);
                int off = ra * 128 + ((ch ^ (ra & 7)) << 4);
                ah[i] = *(const sh8*)(lds + off);
                al[i] = *(const sh8*)(lds + 16384 + off);
            }
            #pragma unroll
            for (int j = 0; j < 4; ++j) {
                int rb = wc * 64 + j * 16 + (lane & 15);
                int off = rb * 128 + ((ch ^ (rb & 7)) << 4);
                bh[j] = *(const sh8*)(lds + 32768 + off);
                bl[j] = *(const sh8*)(lds + 49152 + off);
            }
            #pragma unroll
            for (int i = 0; i < 4; ++i)
                #pragma unroll
                for (int j = 0; j < 4; ++j) {
                    acc[i][j] = __builtin_amdgcn_mfma_f32_16x16x32_bf16(ah[i], bh[j], acc[i][j], 0, 0, 0);
                    acc[i][j] = __builtin_amdgcn_mfma_f32_16x16x32_bf16(ah[i], bl[j], acc[i][j], 0, 0, 0);
                    acc[i][j] = __builtin_amdgcn_mfma_f32_16x16x32_bf16(al[i], bh[j], acc[i][j], 0, 0, 0);
                }
        }
        __syncthreads();
    }
    int lane15 = lane & 15, lg = lane >> 4;
    int gcol[4];
    double ccv[4];
    #pragma unroll
    for (int j = 0; j < 4; ++j) {
        gcol[j] = bkn * 128 + wc * 64 + j * 16 + lane15;
        ccv[j] = cc[gcol[j]];
    }
    #pragma unroll
    for (int i = 0; i < 4; ++i)
        #pragma unroll
        for (int r = 0; r < 4; ++r) {
            int grow = bm * 128 + wr * 64 + i * 16 + lg * 4 + r;
            double zv = (double)zz[grow];
            size_t rowoff = (size_t)grow << 10;
            #pragma unroll
            for (int j = 0; j < 4; ++j)
                nd[rowoff + gcol[j]] = (float)(2.0 * (double)acc[i][j][r] - zv - ccv[j]);
        }
}

// Argmax of (nd+zz)*10 + gumbel (bit-identical to prior rounds). Also tracks the
// winner's nd value: per-row Sum(c-z)^2 == -nd[n,idx_n], accumulated into lossb.
__global__ __launch_bounds__(256) void k_sample(const float* __restrict__ nd, const float* __restrict__ zz,
                                                int* __restrict__ idx, int* __restrict__ counts,
                                                double* __restrict__ lossb) {
    int n = blockIdx.x;
    int t = threadIdx.x;
    float zzn0 = zz[n], zzn1 = zz[n + 32768];
    float best0 = -1e30f, best1 = -1e30f;
    float bn0 = 0.f, bn1 = 0.f;
    int bi0 = 0, bi1 = 0;
    for (int k = t; k < KCB; k += 256) {
        uint32_t ctr = (uint32_t)(n * KCB + k);
        uint32_t r0, r1;
        threefry(ctr, ctr + HALFCNT, r0, r1);
        float g0 = gumbel_f32(r0), g1 = gumbel_f32(r1);
        float nd0 = nd[(size_t)n * KCB + k];
        float nd1 = nd[(size_t)(n + 32768) * KCB + k];
        float s0 = (nd0 + zzn0) * 10.0f + g0;
        float s1 = (nd1 + zzn1) * 10.0f + g1;
        if (s0 > best0) { best0 = s0; bi0 = k; bn0 = nd0; }
        if (s1 > best1) { best1 = s1; bi1 = k; bn1 = nd1; }
    }
    __shared__ float sv0[256], sv1[256], sn0[256], sn1[256];
    __shared__ int si0[256], si1[256];
    sv0[t] = best0; si0[t] = bi0; sn0[t] = bn0;
    sv1[t] = best1; si1[t] = bi1; sn1[t] = bn1;
    __syncthreads();
    for (int off = 128; off; off >>= 1) {
        if (t < off) {
            if (sv0[t + off] > sv0[t] || (sv0[t + off] == sv0[t] && si0[t + off] < si0[t])) {
                sv0[t] = sv0[t + off]; si0[t] = si0[t + off]; sn0[t] = sn0[t + off];
            }
            if (sv1[t + off] > sv1[t] || (sv1[t + off] == sv1[t] && si1[t + off] < si1[t])) {
                sv1[t] = sv1[t + off]; si1[t] = si1[t + off]; sn1[t] = sn1[t + off];
            }
        }
        __syncthreads();
    }
    if (t == 0) {
        idx[n] = si0[0];
        idx[n + 32768] = si1[0];
        atomicAdd(&counts[si0[0]], 1);
        atomicAdd(&counts[si1[0]], 1);
        atomicAdd(&lossb[n & 255], -(double)sn0[0] - (double)sn1[0]);
    }
}

// enc one-hot rows written directly (zero + 1.0 in one coalesced pass) and qz = cb[idx].
__global__ __launch_bounds__(256) void k_enc(const int* __restrict__ idx, const float* __restrict__ cb,
                                             float* __restrict__ enc, float* __restrict__ qz) {
    int t = threadIdx.x;
    int n0 = blockIdx.x * 16;
    __shared__ int si[16];
    if (t < 16) si[t] = idx[n0 + t];
    __syncthreads();
    #pragma unroll
    for (int r = 0; r < 16; ++r) {
        int id = si[r];
        int base = t * 4;
        float4 v;
        v.x = (id == base)     ? 1.0f : 0.0f;
        v.y = (id == base + 1) ? 1.0f : 0.0f;
        v.z = (id == base + 2) ? 1.0f : 0.0f;
        v.w = (id == base + 3) ? 1.0f : 0.0f;
        *(float4*)&enc[(size_t)(n0 + r) * KCB + base] = v;
    }
    for (int e = t; e < 16 * 128; e += 256) {
        int r = e >> 7, s = e & 127;
        *(float4*)&qz[(size_t)(n0 + r) * FD + s * 4] =
            *(const float4*)&cb[(size_t)si[r] * FD + s * 4];
    }
}

__global__ void k_scalars(const int* __restrict__ counts, const double* __restrict__ lossb,
                          float* __restrict__ out) {
    int t = threadIdx.x;
    double s = 0.0;
    for (int k = t; k < KCB; k += 256) {
        double p = (double)counts[k] * (1.0 / 65536.0);
        s += p * log(p + 1e-10);
    }
    double lsum = lossb[t];
    for (int off = 32; off; off >>= 1) {
        s += __shfl_down(s, off, 64);
        lsum += __shfl_down(lsum, off, 64);
    }
    __shared__ double red[4], redl[4];
    int lane = t & 63, w = t >> 6;
    if (lane == 0) { red[w] = s; redl[w] = lsum; }
    __syncthreads();
    if (t == 0) {
        double tot = red[0] + red[1] + red[2] + red[3];
        double ltot = redl[0] + redl[1] + redl[2] + redl[3];
        out[OFF_PERP] = (float)exp(-tot);
        out[0] = (float)(ltot * (2.0 / 33554432.0));
    }
}

extern "C" void kernel_launch(void* const* d_in, const int* in_sizes, int n_in,
                              void* d_out, int out_size, void* d_ws, size_t ws_size,
                              hipStream_t stream) {
    const float* X  = (const float*)d_in[0];
    const float* W1 = (const float*)d_in[1];
    const float* b1 = (const float*)d_in[2];
    const float* W2 = (const float*)d_in[3];
    const float* b2 = (const float*)d_in[4];
    const float* cb = (const float*)d_in[5];

    float* out = (float*)d_out;
    float* qz  = out + (size_t)OFF_Q;
    float* enc = out + (size_t)OFF_ENC;
    float* nd  = out + (size_t)OFF_ND;

    // Small scratch always in ws (<1 MB). Big bf16 scratch (~171 MB): ws if it fits,
    // else the enc output region (dead until k_enc).
    float* zz = (float*)d_ws;            // [65536]
    double* cc = (double*)(zz + 65536);  // [1024]
    double* lossb = cc + 1024;           // [256]
    int* counts = (int*)(lossb + 256);   // [1024]
    int* idx = counts + 1024;            // [65536]

    bool big_ws = ws_size >= ((size_t)200 << 20);
    ushort* ub = big_ws ? (ushort*)((char*)d_ws + (1 << 20)) : (ushort*)(enc + 2);
    ushort* zbh  = ub;                           // [65536*512]
    ushort* zbl  = ub + 33554432;
    ushort* cbh  = ub + 67108864;                // [1024*512]
    ushort* cbl  = ub + 67633152;
    ushort* hh   = ub + 68157440;                // [65536*128]
    ushort* hl   = ub + 76546048;
    ushort* w1th = ub + 84934656;                // [128*1024]
    ushort* w1tl = ub + 85065728;
    ushort* w2th = ub + 85196800;                // [512*128]
    ushort* w2tl = ub + 85262336;

    k_prep<<<641, 256, 0, stream>>>(cb, W1, W2, cbh, cbl, cc, w1th, w1tl, w2th, w2tl, counts, lossb);
    kA<<<512, 256, 0, stream>>>(X, w1th, w1tl, b1, hh, hl);
    kB<<<2048, 256, 0, stream>>>(hh, hl, w2th, w2tl, b2, zbh, zbl, zz);
    k_mfma3<<<4096, 256, 0, stream>>>(zbh, zbl, cbh, cbl, zz, cc, nd);
    k_sample<<<32768, 256, 0, stream>>>(nd, zz, idx, counts, lossb);
    k_enc<<<4096, 256, 0, stream>>>(idx, cb, enc, qz);
    k_scalars<<<1, 256, 0, stream>>>(counts, lossb, out);
}

// Round 6
// 472.847 us; speedup vs baseline: 7.9657x; 1.3346x over previous
//
#include <hip/hip_runtime.h>
#include <stdint.h>

#define N_ROWS 65536
#define DIM 1024
#define HID 128
#define FD 512
#define KCB 1024
#define HALFCNT 33554432u

#define OFF_Q    1
#define OFF_PERP 33554433
#define OFF_ENC  33554434
#define OFF_ND   100663298

typedef __attribute__((ext_vector_type(8))) short sh8;     // 8 bf16 in 4 VGPRs
typedef __attribute__((ext_vector_type(4))) float f32x4;

__device__ __forceinline__ uint32_t rotl32(uint32_t v, int r) { return (v << r) | (v >> (32 - r)); }

// JAX threefry2x32 with key (0, 42)
__device__ __forceinline__ void threefry(uint32_t c0, uint32_t c1, uint32_t& o0, uint32_t& o1) {
    const uint32_t ks0 = 0u, ks1 = 42u, ks2 = 0x1BD11BDAu ^ 0u ^ 42u;
    uint32_t x0 = c0 + ks0, x1 = c1 + ks1;
#define TFR(r) x0 += x1; x1 = rotl32(x1, r); x1 ^= x0;
    TFR(13) TFR(15) TFR(26) TFR(6)  x0 += ks1; x1 += ks2 + 1u;
    TFR(17) TFR(29) TFR(16) TFR(24) x0 += ks2; x1 += ks0 + 2u;
    TFR(13) TFR(15) TFR(26) TFR(6)  x0 += ks0; x1 += ks1 + 3u;
    TFR(17) TFR(29) TFR(16) TFR(24) x0 += ks1; x1 += ks2 + 4u;
    TFR(13) TFR(15) TFR(26) TFR(6)  x0 += ks2; x1 += ks0 + 5u;
#undef TFR
    o0 = x0; o1 = x1;
}

// gumbel via hw v_log_f32: g = -ln(-ln u) = -ln2*log2(-ln2*log2(u)).
// Worst-case error ~0.7 only for u within 2^-24 of 1 (~8 samples device-wide): tolerated.
__device__ __forceinline__ float gumbel_f32(uint32_t b) {
    uint32_t m = b >> 9;
    float u = m ? (float)m * 1.1920928955078125e-07f : 1.17549435e-38f;
    const float LN2 = 0.6931471805599453f;
    return -LN2 * __log2f(-LN2 * __log2f(u));
}

__device__ __forceinline__ ushort bf16rne(float f) {
    uint32_t u = __float_as_uint(f);
    return (ushort)((u + 0x7FFFu + ((u >> 16) & 1u)) >> 16);
}
__device__ __forceinline__ uint32_t pack2rne(float a, float b) {
    return (uint32_t)bf16rne(a) | ((uint32_t)bf16rne(b) << 16);
}

// async global->LDS, 16B per lane; LDS dest = wave-uniform base + lane*16
__device__ __forceinline__ void async_cp16(const void* g, void* l) {
    __builtin_amdgcn_global_load_lds(
        (const __attribute__((address_space(1))) void*)g,
        (__attribute__((address_space(3))) void*)l, 16, 0, 0);
}

// Fused prep: [0,256) codebook bf16(rne)+f64 norms; [256,384) W1T; [384,640) W2T; [640] zero.
__global__ __launch_bounds__(256) void k_prep(const float* __restrict__ cb, const float* __restrict__ W1,
                                              const float* __restrict__ W2,
                                              ushort* __restrict__ cbh, double* __restrict__ cc,
                                              ushort* __restrict__ w1th, ushort* __restrict__ w2th,
                                              int* __restrict__ counts, double* __restrict__ lossb) {
    int gb = blockIdx.x, t = threadIdx.x;
    if (gb < 256) {
        int k = gb * 4 + (t >> 6), l = t & 63;
        const float4* row = (const float4*)(cb + (size_t)k * FD);
        float4 a = row[l * 2], b = row[l * 2 + 1];
        float v[8] = {a.x, a.y, a.z, a.w, b.x, b.y, b.z, b.w};
        double s = 0.0;
        uint32_t hu[4];
        #pragma unroll
        for (int e = 0; e < 4; ++e) {
            hu[e] = pack2rne(v[2 * e], v[2 * e + 1]);
            s = fma((double)v[2 * e], (double)v[2 * e], s);
            s = fma((double)v[2 * e + 1], (double)v[2 * e + 1], s);
        }
        *(uint4*)(cbh + (size_t)k * FD + l * 8) = make_uint4(hu[0], hu[1], hu[2], hu[3]);
        for (int off = 32; off; off >>= 1) s += __shfl_down(s, off, 64);
        if (l == 0) cc[k] = s;
    } else if (gb < 384) {
        int c = gb - 256;
        #pragma unroll
        for (int u = 0; u < 4; ++u) {
            int k = t + u * 256;
            w1th[(size_t)c * DIM + k] = bf16rne(W1[(size_t)k * HID + c]);
        }
    } else if (gb < 640) {
        int c = (gb - 384) * 2 + (t >> 7);
        int tt = t & 127;
        w2th[(size_t)c * HID + tt] = bf16rne(W2[(size_t)tt * FD + c]);
    } else {
        for (int k = t; k < KCB; k += 256) counts[k] = 0;
        lossb[t] = 0.0;
    }
}

// kA: h = relu(X @ W1 + b1), single-product bf16 MFMA. 128x128/block.
__global__ __launch_bounds__(256) void kA(const float* __restrict__ X, const ushort* __restrict__ w1th,
                                          const float* __restrict__ b1, ushort* __restrict__ hh) {
    __shared__ __align__(16) char lds[32768];   // xh | wh (16 KB each)
    int t = threadIdx.x;
    int lane = t & 63, w = t >> 6;
    int wr = w >> 1, wc = w & 1;
    int n0 = blockIdx.x * 128;
    f32x4 zero4 = {0.f, 0.f, 0.f, 0.f};
    f32x4 acc[4][4];
    #pragma unroll
    for (int i = 0; i < 4; ++i)
        #pragma unroll
        for (int j = 0; j < 4; ++j) acc[i][j] = zero4;

    int xr = t >> 1;
    int cb0 = (t & 1) * 4;
    int xsw = xr & 7;

    for (int k0 = 0; k0 < DIM; k0 += 64) {
        #pragma unroll
        for (int i = 0; i < 4; ++i) {
            int rr = w * 32 + i * 8;
            int row = rr + (lane >> 3);
            int csrc = (lane & 7) ^ (row & 7);
            size_t goff = (size_t)row * DIM + k0 + csrc * 8;
            async_cp16(w1th + goff, lds + 16384 + rr * 128);
        }
        const float* xp = X + (size_t)(n0 + xr) * DIM + k0 + cb0 * 8;
        #pragma unroll
        for (int c = 0; c < 4; ++c) {
            float4 a = *(const float4*)(xp + c * 8);
            float4 b = *(const float4*)(xp + c * 8 + 4);
            uint4 hv;
            hv.x = pack2rne(a.x, a.y);
            hv.y = pack2rne(a.z, a.w);
            hv.z = pack2rne(b.x, b.y);
            hv.w = pack2rne(b.z, b.w);
            int slot = xr * 128 + (((cb0 + c) ^ xsw) << 4);
            *(uint4*)(lds + slot) = hv;
        }
        __syncthreads();
        #pragma unroll
        for (int kh = 0; kh < 2; ++kh) {
            int ch = kh * 4 + (lane >> 4);
            sh8 ah[4], bh[4];
            #pragma unroll
            for (int i = 0; i < 4; ++i) {
                int ra = wr * 64 + i * 16 + (lane & 15);
                ah[i] = *(const sh8*)(lds + ra * 128 + ((ch ^ (ra & 7)) << 4));
            }
            #pragma unroll
            for (int j = 0; j < 4; ++j) {
                int rb = wc * 64 + j * 16 + (lane & 15);
                bh[j] = *(const sh8*)(lds + 16384 + rb * 128 + ((ch ^ (rb & 7)) << 4));
            }
            #pragma unroll
            for (int i = 0; i < 4; ++i)
                #pragma unroll
                for (int j = 0; j < 4; ++j)
                    acc[i][j] = __builtin_amdgcn_mfma_f32_16x16x32_bf16(ah[i], bh[j], acc[i][j], 0, 0, 0);
        }
        __syncthreads();
    }
    int lane15 = lane & 15, lg = lane >> 4;
    #pragma unroll
    for (int j = 0; j < 4; ++j) {
        int gcol = wc * 64 + j * 16 + lane15;
        float b1v = b1[gcol];
        #pragma unroll
        for (int i = 0; i < 4; ++i)
            #pragma unroll
            for (int r = 0; r < 4; ++r) {
                int grow = n0 + wr * 64 + i * 16 + lg * 4 + r;
                hh[(size_t)grow * HID + gcol] = bf16rne(fmaxf(acc[i][j][r] + b1v, 0.f));
            }
    }
}

// kB: z = h @ W2 + b2, single-product bf16 MFMA. 32 rows/block, K=128; writes zbh + zz.
__global__ __launch_bounds__(256) void kB(const ushort* __restrict__ hh, const ushort* __restrict__ w2th,
                                          const float* __restrict__ b2,
                                          ushort* __restrict__ zbh, float* __restrict__ zz) {
    __shared__ __align__(16) char lds[8192];
    __shared__ float zzp[4][32];
    int t = threadIdx.x;
    int lane = t & 63, w = t >> 6;
    int n0 = blockIdx.x * 32;
    #pragma unroll
    for (int i = 0; i < 2; ++i) {
        int rr = w * 8 + i * 4;
        int row = rr + (lane >> 4);
        int csrc = (lane & 15) ^ (row & 7);
        size_t goff = (size_t)(n0 + row) * HID + csrc * 8;
        async_cp16(hh + goff, lds + rr * 256);
    }
    f32x4 zero4 = {0.f, 0.f, 0.f, 0.f};
    f32x4 acc[2][8];
    #pragma unroll
    for (int i = 0; i < 2; ++i)
        #pragma unroll
        for (int j = 0; j < 8; ++j) acc[i][j] = zero4;
    __syncthreads();
    #pragma unroll
    for (int kh = 0; kh < 4; ++kh) {
        int ch = kh * 4 + (lane >> 4);
        sh8 ah[2];
        #pragma unroll
        for (int i = 0; i < 2; ++i) {
            int ra = i * 16 + (lane & 15);
            ah[i] = *(const sh8*)(lds + ra * 256 + ((ch ^ (ra & 7)) << 4));
        }
        #pragma unroll
        for (int j = 0; j < 8; ++j) {
            int col = w * 128 + j * 16 + (lane & 15);
            sh8 bh = *(const sh8*)(w2th + (size_t)col * HID + ch * 8);
            #pragma unroll
            for (int i = 0; i < 2; ++i)
                acc[i][j] = __builtin_amdgcn_mfma_f32_16x16x32_bf16(ah[i], bh, acc[i][j], 0, 0, 0);
        }
    }
    int lane15 = lane & 15, lg = lane >> 4;
    float b2v[8];
    #pragma unroll
    for (int j = 0; j < 8; ++j) b2v[j] = b2[w * 128 + j * 16 + lane15];
    #pragma unroll
    for (int i = 0; i < 2; ++i)
        #pragma unroll
        for (int r = 0; r < 4; ++r) {
            int lrow = i * 16 + lg * 4 + r;
            size_t rowb = (size_t)(n0 + lrow) * FD;
            float s = 0.f;
            #pragma unroll
            for (int j = 0; j < 8; ++j) {
                float v = acc[i][j][r] + b2v[j];
                zbh[rowb + w * 128 + j * 16 + lane15] = bf16rne(v);
                s = fmaf(v, v, s);
            }
            s += __shfl_xor(s, 1, 64); s += __shfl_xor(s, 2, 64);
            s += __shfl_xor(s, 4, 64); s += __shfl_xor(s, 8, 64);
            if (lane15 == 0) zzp[w][lrow] = s;
        }
    __syncthreads();
    if (t < 32) zz[n0 + t] = zzp[0][t] + zzp[1][t] + zzp[2][t] + zzp[3][t];
}

// Distance GEMM, single-product bf16 MFMA. nd = 2*dot - zz - cc.
__global__ __launch_bounds__(256) void k_mfma3(const ushort* __restrict__ zbh, const ushort* __restrict__ cbh,
                                               const float* __restrict__ zz, const double* __restrict__ cc,
                                               float* __restrict__ nd) {
    __shared__ __align__(16) char lds[32768];   // Ah | Bh (16 KB each)
    int t = threadIdx.x;
    int lane = t & 63, w = t >> 6;
    int wr = w >> 1, wc = w & 1;
    int bid = blockIdx.x;
    int bm = ((bid >> 6) << 3) | (bid & 7);
    int bkn = (bid >> 3) & 7;
    const ushort* Ahg = zbh + (size_t)bm * 128 * FD;
    const ushort* Bhg = cbh + (size_t)bkn * 128 * FD;

    f32x4 zero4 = {0.f, 0.f, 0.f, 0.f};
    f32x4 acc[4][4];
    #pragma unroll
    for (int i = 0; i < 4; ++i)
        #pragma unroll
        for (int j = 0; j < 4; ++j) acc[i][j] = zero4;

    for (int k0 = 0; k0 < FD; k0 += 64) {
        #pragma unroll
        for (int i = 0; i < 4; ++i) {
            int rr = w * 32 + i * 8;
            int row = rr + (lane >> 3);
            int csrc = (lane & 7) ^ (row & 7);
            size_t goff = (size_t)row * FD + k0 + csrc * 8;
            async_cp16(Ahg + goff, lds + rr * 128);
            async_cp16(Bhg + goff, lds + 16384 + rr * 128);
        }
        __syncthreads();
        #pragma unroll
        for (int kh = 0; kh < 2; ++kh) {
            int ch = kh * 4 + (lane >> 4);
            sh8 ah[4], bh[4];
            #pragma unroll
            for (int i = 0; i < 4; ++i) {
                int ra = wr * 64 + i * 16 + (lane & 15);
                ah[i] = *(const sh8*)(lds + ra * 128 + ((ch ^ (ra & 7)) << 4));
            }
            #pragma unroll
            for (int j = 0; j < 4; ++j) {
                int rb = wc * 64 + j * 16 + (lane & 15);
                bh[j] = *(const sh8*)(lds + 16384 + rb * 128 + ((ch ^ (rb & 7)) << 4));
            }
            #pragma unroll
            for (int i = 0; i < 4; ++i)
                #pragma unroll
                for (int j = 0; j < 4; ++j)
                    acc[i][j] = __builtin_amdgcn_mfma_f32_16x16x32_bf16(ah[i], bh[j], acc[i][j], 0, 0, 0);
        }
        __syncthreads();
    }
    int lane15 = lane & 15, lg = lane >> 4;
    int gcol[4];
    double ccv[4];
    #pragma unroll
    for (int j = 0; j < 4; ++j) {
        gcol[j] = bkn * 128 + wc * 64 + j * 16 + lane15;
        ccv[j] = cc[gcol[j]];
    }
    #pragma unroll
    for (int i = 0; i < 4; ++i)
        #pragma unroll
        for (int r = 0; r < 4; ++r) {
            int grow = bm * 128 + wr * 64 + i * 16 + lg * 4 + r;
            double zv = (double)zz[grow];
            size_t rowoff = (size_t)grow << 10;
            #pragma unroll
            for (int j = 0; j < 4; ++j)
                nd[rowoff + gcol[j]] = (float)(2.0 * (double)acc[i][j][r] - zv - ccv[j]);
        }
}

// Argmax of (nd+zz)*10 + gumbel; winner's -nd accumulates the loss.
__global__ __launch_bounds__(256) void k_sample(const float* __restrict__ nd, const float* __restrict__ zz,
                                                int* __restrict__ idx, int* __restrict__ counts,
                                                double* __restrict__ lossb) {
    int n = blockIdx.x;
    int t = threadIdx.x;
    float zzn0 = zz[n], zzn1 = zz[n + 32768];
    float best0 = -1e30f, best1 = -1e30f;
    float bn0 = 0.f, bn1 = 0.f;
    int bi0 = 0, bi1 = 0;
    for (int k = t; k < KCB; k += 256) {
        uint32_t ctr = (uint32_t)(n * KCB + k);
        uint32_t r0, r1;
        threefry(ctr, ctr + HALFCNT, r0, r1);
        float g0 = gumbel_f32(r0), g1 = gumbel_f32(r1);
        float nd0 = nd[(size_t)n * KCB + k];
        float nd1 = nd[(size_t)(n + 32768) * KCB + k];
        float s0 = (nd0 + zzn0) * 10.0f + g0;
        float s1 = (nd1 + zzn1) * 10.0f + g1;
        if (s0 > best0) { best0 = s0; bi0 = k; bn0 = nd0; }
        if (s1 > best1) { best1 = s1; bi1 = k; bn1 = nd1; }
    }
    __shared__ float sv0[256], sv1[256], sn0[256], sn1[256];
    __shared__ int si0[256], si1[256];
    sv0[t] = best0; si0[t] = bi0; sn0[t] = bn0;
    sv1[t] = best1; si1[t] = bi1; sn1[t] = bn1;
    __syncthreads();
    for (int off = 128; off; off >>= 1) {
        if (t < off) {
            if (sv0[t + off] > sv0[t] || (sv0[t + off] == sv0[t] && si0[t + off] < si0[t])) {
                sv0[t] = sv0[t + off]; si0[t] = si0[t + off]; sn0[t] = sn0[t + off];
            }
            if (sv1[t + off] > sv1[t] || (sv1[t + off] == sv1[t] && si1[t + off] < si1[t])) {
                sv1[t] = sv1[t + off]; si1[t] = si1[t + off]; sn1[t] = sn1[t + off];
            }
        }
        __syncthreads();
    }
    if (t == 0) {
        idx[n] = si0[0];
        idx[n + 32768] = si1[0];
        atomicAdd(&counts[si0[0]], 1);
        atomicAdd(&counts[si1[0]], 1);
        atomicAdd(&lossb[n & 255], -(double)sn0[0] - (double)sn1[0]);
    }
}

// enc one-hot rows written directly and qz = cb[idx].
__global__ __launch_bounds__(256) void k_enc(const int* __restrict__ idx, const float* __restrict__ cb,
                                             float* __restrict__ enc, float* __restrict__ qz) {
    int t = threadIdx.x;
    int n0 = blockIdx.x * 16;
    __shared__ int si[16];
    if (t < 16) si[t] = idx[n0 + t];
    __syncthreads();
    #pragma unroll
    for (int r = 0; r < 16; ++r) {
        int id = si[r];
        int base = t * 4;
        float4 v;
        v.x = (id == base)     ? 1.0f : 0.0f;
        v.y = (id == base + 1) ? 1.0f : 0.0f;
        v.z = (id == base + 2) ? 1.0f : 0.0f;
        v.w = (id == base + 3) ? 1.0f : 0.0f;
        *(float4*)&enc[(size_t)(n0 + r) * KCB + base] = v;
    }
    for (int e = t; e < 16 * 128; e += 256) {
        int r = e >> 7, s = e & 127;
        *(float4*)&qz[(size_t)(n0 + r) * FD + s * 4] =
            *(const float4*)&cb[(size_t)si[r] * FD + s * 4];
    }
}

__global__ void k_scalars(const int* __restrict__ counts, const double* __restrict__ lossb,
                          float* __restrict__ out) {
    int t = threadIdx.x;
    double s = 0.0;
    for (int k = t; k < KCB; k += 256) {
        double p = (double)counts[k] * (1.0 / 65536.0);
        s += p * log(p + 1e-10);
    }
    double lsum = lossb[t];
    for (int off = 32; off; off >>= 1) {
        s += __shfl_down(s, off, 64);
        lsum += __shfl_down(lsum, off, 64);
    }
    __shared__ double red[4], redl[4];
    int lane = t & 63, w = t >> 6;
    if (lane == 0) { red[w] = s; redl[w] = lsum; }
    __syncthreads();
    if (t == 0) {
        double tot = red[0] + red[1] + red[2] + red[3];
        double ltot = redl[0] + redl[1] + redl[2] + redl[3];
        out[OFF_PERP] = (float)exp(-tot);
        out[0] = (float)(ltot * (2.0 / 33554432.0));
    }
}

extern "C" void kernel_launch(void* const* d_in, const int* in_sizes, int n_in,
                              void* d_out, int out_size, void* d_ws, size_t ws_size,
                              hipStream_t stream) {
    const float* X  = (const float*)d_in[0];
    const float* W1 = (const float*)d_in[1];
    const float* b1 = (const float*)d_in[2];
    const float* W2 = (const float*)d_in[3];
    const float* b2 = (const float*)d_in[4];
    const float* cb = (const float*)d_in[5];

    float* out = (float*)d_out;
    float* qz  = out + (size_t)OFF_Q;
    float* enc = out + (size_t)OFF_ENC;
    float* nd  = out + (size_t)OFF_ND;

    float* zz = (float*)d_ws;            // [65536]
    double* cc = (double*)(zz + 65536);  // [1024]
    double* lossb = cc + 1024;           // [256]
    int* counts = (int*)(lossb + 256);   // [1024]
    int* idx = counts + 1024;            // [65536]

    bool big_ws = ws_size >= ((size_t)100 << 20);
    ushort* ub = big_ws ? (ushort*)((char*)d_ws + (1 << 20)) : (ushort*)(enc + 2);
    ushort* zbh  = ub;                   // [65536*512]
    ushort* cbh  = ub + 33554432;        // [1024*512]
    ushort* hh   = ub + 34078720;        // [65536*128]
    ushort* w1th = ub + 42467328;        // [128*1024]
    ushort* w2th = ub + 42598400;        // [512*128]

    k_prep<<<641, 256, 0, stream>>>(cb, W1, W2, cbh, cc, w1th, w2th, counts, lossb);
    kA<<<512, 256, 0, stream>>>(X, w1th, b1, hh);
    kB<<<2048, 256, 0, stream>>>(hh, w2th, b2, zbh, zz);
    k_mfma3<<<4096, 256, 0, stream>>>(zbh, cbh, zz, cc, nd);
    k_sample<<<32768, 256, 0, stream>>>(nd, zz, idx, counts, lossb);
    k_enc<<<4096, 256, 0, stream>>>(idx, cb, enc, qz);
    k_scalars<<<1, 256, 0, stream>>>(counts, lossb, out);
}

// Round 7
// 472.088 us; speedup vs baseline: 7.9785x; 1.0016x over previous
//
#include <hip/hip_runtime.h>
#include <stdint.h>

#define N_ROWS 65536
#define DIM 1024
#define HID 128
#define FD 512
#define KCB 1024
#define HALFCNT 33554432u

#define OFF_Q    1
#define OFF_PERP 33554433
#define OFF_ENC  33554434
#define OFF_ND   100663298

typedef __attribute__((ext_vector_type(8))) short sh8;     // 8 bf16 in 4 VGPRs
typedef __attribute__((ext_vector_type(4))) float f32x4;

__device__ __forceinline__ uint32_t rotl32(uint32_t v, int r) { return (v << r) | (v >> (32 - r)); }

// JAX threefry2x32 with key (0, 42)
__device__ __forceinline__ void threefry(uint32_t c0, uint32_t c1, uint32_t& o0, uint32_t& o1) {
    const uint32_t ks0 = 0u, ks1 = 42u, ks2 = 0x1BD11BDAu ^ 0u ^ 42u;
    uint32_t x0 = c0 + ks0, x1 = c1 + ks1;
#define TFR(r) x0 += x1; x1 = rotl32(x1, r); x1 ^= x0;
    TFR(13) TFR(15) TFR(26) TFR(6)  x0 += ks1; x1 += ks2 + 1u;
    TFR(17) TFR(29) TFR(16) TFR(24) x0 += ks2; x1 += ks0 + 2u;
    TFR(13) TFR(15) TFR(26) TFR(6)  x0 += ks0; x1 += ks1 + 3u;
    TFR(17) TFR(29) TFR(16) TFR(24) x0 += ks1; x1 += ks2 + 4u;
    TFR(13) TFR(15) TFR(26) TFR(6)  x0 += ks2; x1 += ks0 + 5u;
#undef TFR
    o0 = x0; o1 = x1;
}

// gumbel via hw v_log_f32 (same bits as round 6)
__device__ __forceinline__ float gumbel_f32(uint32_t b) {
    uint32_t m = b >> 9;
    float u = m ? (float)m * 1.1920928955078125e-07f : 1.17549435e-38f;
    const float LN2 = 0.6931471805599453f;
    return -LN2 * __log2f(-LN2 * __log2f(u));
}

__device__ __forceinline__ ushort bf16rne(float f) {
    uint32_t u = __float_as_uint(f);
    return (ushort)((u + 0x7FFFu + ((u >> 16) & 1u)) >> 16);
}
__device__ __forceinline__ uint32_t pack2rne(float a, float b) {
    return (uint32_t)bf16rne(a) | ((uint32_t)bf16rne(b) << 16);
}

// async global->LDS, 16B per lane
__device__ __forceinline__ void async_cp16(const void* g, void* l) {
    __builtin_amdgcn_global_load_lds(
        (const __attribute__((address_space(1))) void*)g,
        (__attribute__((address_space(3))) void*)l, 16, 0, 0);
}

// Fused prep: [0,256) codebook bf16+f64 norms; [256,384) W1T; [384,640) W2T; [640] zero.
__global__ __launch_bounds__(256) void k_prep(const float* __restrict__ cb, const float* __restrict__ W1,
                                              const float* __restrict__ W2,
                                              ushort* __restrict__ cbh, double* __restrict__ cc,
                                              ushort* __restrict__ w1th, ushort* __restrict__ w2th,
                                              int* __restrict__ counts, double* __restrict__ lossb) {
    int gb = blockIdx.x, t = threadIdx.x;
    if (gb < 256) {
        int k = gb * 4 + (t >> 6), l = t & 63;
        const float4* row = (const float4*)(cb + (size_t)k * FD);
        float4 a = row[l * 2], b = row[l * 2 + 1];
        float v[8] = {a.x, a.y, a.z, a.w, b.x, b.y, b.z, b.w};
        double s = 0.0;
        uint32_t hu[4];
        #pragma unroll
        for (int e = 0; e < 4; ++e) {
            hu[e] = pack2rne(v[2 * e], v[2 * e + 1]);
            s = fma((double)v[2 * e], (double)v[2 * e], s);
            s = fma((double)v[2 * e + 1], (double)v[2 * e + 1], s);
        }
        *(uint4*)(cbh + (size_t)k * FD + l * 8) = make_uint4(hu[0], hu[1], hu[2], hu[3]);
        for (int off = 32; off; off >>= 1) s += __shfl_down(s, off, 64);
        if (l == 0) cc[k] = s;
    } else if (gb < 384) {
        int c = gb - 256;
        #pragma unroll
        for (int u = 0; u < 4; ++u) {
            int k = t + u * 256;
            w1th[(size_t)c * DIM + k] = bf16rne(W1[(size_t)k * HID + c]);
        }
    } else if (gb < 640) {
        int c = (gb - 384) * 2 + (t >> 7);
        int tt = t & 127;
        w2th[(size_t)c * HID + tt] = bf16rne(W2[(size_t)tt * FD + c]);
    } else {
        for (int k = t; k < KCB; k += 256) counts[k] = 0;
        lossb[t] = 0.0;
    }
}

// Fused MLP: phase1 h = relu(X@W1+b1) -> bf16 in LDS; phase2 z = h@W2+b2 -> zbh + zz.
// 128 rows/block. Phase-2 B-fragments stream from L2-resident w2th.
__global__ __launch_bounds__(256) void kAB(const float* __restrict__ X, const ushort* __restrict__ w1th,
                                           const float* __restrict__ b1, const ushort* __restrict__ w2th,
                                           const float* __restrict__ b2,
                                           ushort* __restrict__ zbh, float* __restrict__ zz) {
    __shared__ __align__(16) char lds[32768];   // phase1: xh|wh; then h[128][128] bf16 swizzled
    __shared__ float zzp[128][2];
    int t = threadIdx.x;
    int lane = t & 63, w = t >> 6;
    int wr = w >> 1, wc = w & 1;
    int lane15 = lane & 15, lg = lane >> 4;
    int n0 = blockIdx.x * 128;
    f32x4 zero4 = {0.f, 0.f, 0.f, 0.f};
    f32x4 acc[4][4];
    #pragma unroll
    for (int i = 0; i < 4; ++i)
        #pragma unroll
        for (int j = 0; j < 4; ++j) acc[i][j] = zero4;

    int xr = t >> 1;
    int cb0 = (t & 1) * 4;
    int xsw = xr & 7;

    for (int k0 = 0; k0 < DIM; k0 += 64) {
        #pragma unroll
        for (int i = 0; i < 4; ++i) {
            int rr = w * 32 + i * 8;
            int row = rr + (lane >> 3);
            int csrc = (lane & 7) ^ (row & 7);
            size_t goff = (size_t)row * DIM + k0 + csrc * 8;
            async_cp16(w1th + goff, lds + 16384 + rr * 128);
        }
        const float* xp = X + (size_t)(n0 + xr) * DIM + k0 + cb0 * 8;
        #pragma unroll
        for (int c = 0; c < 4; ++c) {
            float4 a = *(const float4*)(xp + c * 8);
            float4 b = *(const float4*)(xp + c * 8 + 4);
            uint4 hv;
            hv.x = pack2rne(a.x, a.y);
            hv.y = pack2rne(a.z, a.w);
            hv.z = pack2rne(b.x, b.y);
            hv.w = pack2rne(b.z, b.w);
            int slot = xr * 128 + (((cb0 + c) ^ xsw) << 4);
            *(uint4*)(lds + slot) = hv;
        }
        __syncthreads();
        #pragma unroll
        for (int kh = 0; kh < 2; ++kh) {
            int ch = kh * 4 + lg;
            sh8 ah[4], bh[4];
            #pragma unroll
            for (int i = 0; i < 4; ++i) {
                int ra = wr * 64 + i * 16 + lane15;
                ah[i] = *(const sh8*)(lds + ra * 128 + ((ch ^ (ra & 7)) << 4));
            }
            #pragma unroll
            for (int j = 0; j < 4; ++j) {
                int rb = wc * 64 + j * 16 + lane15;
                bh[j] = *(const sh8*)(lds + 16384 + rb * 128 + ((ch ^ (rb & 7)) << 4));
            }
            #pragma unroll
            for (int i = 0; i < 4; ++i)
                #pragma unroll
                for (int j = 0; j < 4; ++j)
                    acc[i][j] = __builtin_amdgcn_mfma_f32_16x16x32_bf16(ah[i], bh[j], acc[i][j], 0, 0, 0);
        }
        __syncthreads();
    }
    // phase-1 epilogue: h (bf16) into LDS [row][128 k], XOR-swizzled, same values as old hh
    #pragma unroll
    for (int j = 0; j < 4; ++j) {
        int hcol = wc * 64 + j * 16 + lane15;
        float b1v = b1[hcol];
        int k8 = hcol >> 3, klo = hcol & 7;
        #pragma unroll
        for (int i = 0; i < 4; ++i)
            #pragma unroll
            for (int r = 0; r < 4; ++r) {
                int row = wr * 64 + i * 16 + lg * 4 + r;
                ushort hb = bf16rne(fmaxf(acc[i][j][r] + b1v, 0.f));
                *(ushort*)(lds + row * 256 + ((k8 ^ (row & 7)) << 4) + klo * 2) = hb;
            }
    }
    __syncthreads();
    // phase 2: z = h @ W2 + b2, 4 chunks of 128 cols; K = 128
    float zsum[16];
    #pragma unroll
    for (int e = 0; e < 16; ++e) zsum[e] = 0.f;
    for (int c2 = 0; c2 < 4; ++c2) {
        f32x4 acc2[4][4];
        #pragma unroll
        for (int i = 0; i < 4; ++i)
            #pragma unroll
            for (int j = 0; j < 4; ++j) acc2[i][j] = zero4;
        #pragma unroll
        for (int kh = 0; kh < 4; ++kh) {
            int ch = kh * 4 + lg;
            sh8 ah[4], bh[4];
            #pragma unroll
            for (int i = 0; i < 4; ++i) {
                int ra = wr * 64 + i * 16 + lane15;
                ah[i] = *(const sh8*)(lds + ra * 256 + ((ch ^ (ra & 7)) << 4));
            }
            #pragma unroll
            for (int j = 0; j < 4; ++j) {
                int col = c2 * 128 + wc * 64 + j * 16 + lane15;
                bh[j] = *(const sh8*)(w2th + (size_t)col * HID + ch * 8);
            }
            #pragma unroll
            for (int i = 0; i < 4; ++i)
                #pragma unroll
                for (int j = 0; j < 4; ++j)
                    acc2[i][j] = __builtin_amdgcn_mfma_f32_16x16x32_bf16(ah[i], bh[j], acc2[i][j], 0, 0, 0);
        }
        #pragma unroll
        for (int j = 0; j < 4; ++j) {
            int col = c2 * 128 + wc * 64 + j * 16 + lane15;
            float b2v = b2[col];
            #pragma unroll
            for (int i = 0; i < 4; ++i)
                #pragma unroll
                for (int r = 0; r < 4; ++r) {
                    int row = wr * 64 + i * 16 + lg * 4 + r;
                    float v = acc2[i][j][r] + b2v;
                    zbh[(size_t)(n0 + row) * FD + col] = bf16rne(v);
                    zsum[i * 4 + r] = fmaf(v, v, zsum[i * 4 + r]);
                }
        }
    }
    #pragma unroll
    for (int e = 0; e < 16; ++e) {
        float s = zsum[e];
        s += __shfl_xor(s, 1, 64); s += __shfl_xor(s, 2, 64);
        s += __shfl_xor(s, 4, 64); s += __shfl_xor(s, 8, 64);
        if (lane15 == 0) zzp[wr * 64 + (e >> 2) * 16 + lg * 4 + (e & 3)][wc] = s;
    }
    __syncthreads();
    if (t < 128) zz[n0 + t] = zzp[t][0] + zzp[t][1];
}

// Distance GEMM + fused gumbel sampling. nd = 2*dot - zz - cc (bit-identical to round 6);
// per (row, bkn, wave) u64 partial argmax key written to `partials` (16/row).
__global__ __launch_bounds__(256) void k_mfma3s(const ushort* __restrict__ zbh, const ushort* __restrict__ cbh,
                                                const float* __restrict__ zz, const double* __restrict__ cc,
                                                float* __restrict__ nd,
                                                unsigned long long* __restrict__ partials) {
    __shared__ __align__(16) char lds[32768];   // Ah | Bh (16 KB each)
    int t = threadIdx.x;
    int lane = t & 63, w = t >> 6;
    int wr = w >> 1, wc = w & 1;
    int bid = blockIdx.x;
    int bm = ((bid >> 6) << 3) | (bid & 7);
    int bkn = (bid >> 3) & 7;
    const ushort* Ahg = zbh + (size_t)bm * 128 * FD;
    const ushort* Bhg = cbh + (size_t)bkn * 128 * FD;

    f32x4 zero4 = {0.f, 0.f, 0.f, 0.f};
    f32x4 acc[4][4];
    #pragma unroll
    for (int i = 0; i < 4; ++i)
        #pragma unroll
        for (int j = 0; j < 4; ++j) acc[i][j] = zero4;

    for (int k0 = 0; k0 < FD; k0 += 64) {
        #pragma unroll
        for (int i = 0; i < 4; ++i) {
            int rr = w * 32 + i * 8;
            int row = rr + (lane >> 3);
            int csrc = (lane & 7) ^ (row & 7);
            size_t goff = (size_t)row * FD + k0 + csrc * 8;
            async_cp16(Ahg + goff, lds + rr * 128);
            async_cp16(Bhg + goff, lds + 16384 + rr * 128);
        }
        __syncthreads();
        #pragma unroll
        for (int kh = 0; kh < 2; ++kh) {
            int ch = kh * 4 + (lane >> 4);
            sh8 ah[4], bh[4];
            #pragma unroll
            for (int i = 0; i < 4; ++i) {
                int ra = wr * 64 + i * 16 + (lane & 15);
                ah[i] = *(const sh8*)(lds + ra * 128 + ((ch ^ (ra & 7)) << 4));
            }
            #pragma unroll
            for (int j = 0; j < 4; ++j) {
                int rb = wc * 64 + j * 16 + (lane & 15);
                bh[j] = *(const sh8*)(lds + 16384 + rb * 128 + ((ch ^ (rb & 7)) << 4));
            }
            #pragma unroll
            for (int i = 0; i < 4; ++i)
                #pragma unroll
                for (int j = 0; j < 4; ++j)
                    acc[i][j] = __builtin_amdgcn_mfma_f32_16x16x32_bf16(ah[i], bh[j], acc[i][j], 0, 0, 0);
        }
        __syncthreads();
    }
    int lane15 = lane & 15, lg = lane >> 4;
    int gcol[4];
    double ccv[4];
    #pragma unroll
    for (int j = 0; j < 4; ++j) {
        gcol[j] = bkn * 128 + wc * 64 + j * 16 + lane15;
        ccv[j] = cc[gcol[j]];
    }
    bool high = bm >= 256;                 // wave-uniform: rows >= 32768 use out1
    uint32_t csub = high ? HALFCNT : 0u;
    #pragma unroll
    for (int i = 0; i < 4; ++i)
        #pragma unroll
        for (int r = 0; r < 4; ++r) {
            int grow = bm * 128 + wr * 64 + i * 16 + lg * 4 + r;
            float zzf = zz[grow];
            double zv = (double)zzf;
            size_t rowoff = (size_t)grow << 10;
            unsigned long long bkey = 0ull;
            #pragma unroll
            for (int j = 0; j < 4; ++j) {
                float ndf = (float)(2.0 * (double)acc[i][j][r] - zv - ccv[j]);
                nd[rowoff + gcol[j]] = ndf;
                uint32_t iflat = (uint32_t)grow * 1024u + (uint32_t)gcol[j];
                uint32_t base = iflat - csub;
                uint32_t r0, r1;
                threefry(base, base + HALFCNT, r0, r1);
                float gv = gumbel_f32(high ? r1 : r0);
                float s = (ndf + zzf) * 10.0f + gv;
                uint32_t ub = __float_as_uint(s);
                ub ^= (uint32_t)(((int32_t)ub >> 31) | 0x80000000);   // monotone float->uint
                unsigned long long key = ((unsigned long long)ub << 32) | (uint32_t)(1023 - gcol[j]);
                if (key > bkey) bkey = key;
            }
            #pragma unroll
            for (int m = 1; m <= 8; m <<= 1) {
                unsigned long long o = __shfl_xor(bkey, m, 64);
                if (o > bkey) bkey = o;
            }
            if (lane15 == 0) partials[(size_t)grow * 16 + bkn * 2 + wc] = bkey;
        }
}

// Finalize: reduce 16 partials/row -> idx; counts/loss atomics (loss = -nd[n,idx]);
// write one-hot enc rows + qz = cb[idx]. 16 rows per block.
__global__ __launch_bounds__(256) void k_enc2(const unsigned long long* __restrict__ partials,
                                              const float* __restrict__ nd, const float* __restrict__ cb,
                                              float* __restrict__ enc, float* __restrict__ qz,
                                              int* __restrict__ counts, double* __restrict__ lossb) {
    int t = threadIdx.x;
    int n0 = blockIdx.x * 16;
    __shared__ int si[16];
    if (t < 16) {
        int n = n0 + t;
        const unsigned long long* p = partials + (size_t)n * 16;
        unsigned long long best = p[0];
        #pragma unroll
        for (int e = 1; e < 16; ++e) {
            unsigned long long v = p[e];
            if (v > best) best = v;
        }
        int k = 1023 - (int)(best & 0xFFFFFFFFull);
        si[t] = k;
        atomicAdd(&counts[k], 1);
        float ndv = nd[(size_t)n * KCB + k];
        atomicAdd(&lossb[n & 255], -(double)ndv);
    }
    __syncthreads();
    #pragma unroll
    for (int r = 0; r < 16; ++r) {
        int id = si[r];
        int base = t * 4;
        float4 v;
        v.x = (id == base)     ? 1.0f : 0.0f;
        v.y = (id == base + 1) ? 1.0f : 0.0f;
        v.z = (id == base + 2) ? 1.0f : 0.0f;
        v.w = (id == base + 3) ? 1.0f : 0.0f;
        *(float4*)&enc[(size_t)(n0 + r) * KCB + base] = v;
    }
    for (int e = t; e < 16 * 128; e += 256) {
        int r = e >> 7, s = e & 127;
        *(float4*)&qz[(size_t)(n0 + r) * FD + s * 4] =
            *(const float4*)&cb[(size_t)si[r] * FD + s * 4];
    }
}

__global__ void k_scalars(const int* __restrict__ counts, const double* __restrict__ lossb,
                          float* __restrict__ out) {
    int t = threadIdx.x;
    double s = 0.0;
    for (int k = t; k < KCB; k += 256) {
        double p = (double)counts[k] * (1.0 / 65536.0);
        s += p * log(p + 1e-10);
    }
    double lsum = lossb[t];
    for (int off = 32; off; off >>= 1) {
        s += __shfl_down(s, off, 64);
        lsum += __shfl_down(lsum, off, 64);
    }
    __shared__ double red[4], redl[4];
    int lane = t & 63, w = t >> 6;
    if (lane == 0) { red[w] = s; redl[w] = lsum; }
    __syncthreads();
    if (t == 0) {
        double tot = red[0] + red[1] + red[2] + red[3];
        double ltot = redl[0] + redl[1] + redl[2] + redl[3];
        out[OFF_PERP] = (float)exp(-tot);
        out[0] = (float)(ltot * (2.0 / 33554432.0));
    }
}

extern "C" void kernel_launch(void* const* d_in, const int* in_sizes, int n_in,
                              void* d_out, int out_size, void* d_ws, size_t ws_size,
                              hipStream_t stream) {
    const float* X  = (const float*)d_in[0];
    const float* W1 = (const float*)d_in[1];
    const float* b1 = (const float*)d_in[2];
    const float* W2 = (const float*)d_in[3];
    const float* b2 = (const float*)d_in[4];
    const float* cb = (const float*)d_in[5];

    float* out = (float*)d_out;
    float* qz  = out + (size_t)OFF_Q;
    float* enc = out + (size_t)OFF_ENC;
    float* nd  = out + (size_t)OFF_ND;

    float* zz = (float*)d_ws;            // [65536]
    double* cc = (double*)(zz + 65536);  // [1024]
    double* lossb = cc + 1024;           // [256]
    int* counts = (int*)(lossb + 256);   // [1024]

    bool big_ws = ws_size >= ((size_t)100 << 20);
    char* big = big_ws ? ((char*)d_ws + (1 << 20)) : (char*)(enc + 2);
    unsigned long long* partials = (unsigned long long*)big;   // [65536*16] = 8 MB
    ushort* ub   = (ushort*)(big + ((size_t)9 << 20));
    ushort* zbh  = ub;                   // [65536*512]
    ushort* cbh  = ub + 33554432;        // [1024*512]
    ushort* w1th = ub + 34078720;        // [128*1024]
    ushort* w2th = ub + 34209792;        // [512*128]

    k_prep<<<641, 256, 0, stream>>>(cb, W1, W2, cbh, cc, w1th, w2th, counts, lossb);
    kAB<<<512, 256, 0, stream>>>(X, w1th, b1, w2th, b2, zbh, zz);
    k_mfma3s<<<4096, 256, 0, stream>>>(zbh, cbh, zz, cc, nd, partials);
    k_enc2<<<4096, 256, 0, stream>>>(partials, nd, cb, enc, qz, counts, lossb);
    k_scalars<<<1, 256, 0, stream>>>(counts, lossb, out);
}